// Round 13
// baseline (110.911 us; speedup 1.0000x reference)
//
#include <hip/hip_runtime.h>
#include <hip/hip_bf16.h>

#define N 1024
#define D 64

typedef __attribute__((ext_vector_type(8))) short bf16x8;
typedef __attribute__((ext_vector_type(4))) float f32x4;

__device__ __forceinline__ unsigned short f2b(float v) {
  unsigned u = __float_as_uint(v);
  u += 0x7fffu + ((u >> 16) & 1u);
  return (unsigned short)(u >> 16);
}
__device__ __forceinline__ unsigned short f2bc(float v) {
  union { __hip_bfloat16 h; unsigned short u; } r;
  r.h = __float2bfloat16(v);
  return r.u;
}
__device__ __forceinline__ unsigned pk2(float a, float b) {
  union { __hip_bfloat162 h; unsigned u; } r;
  r.h = __hip_bfloat162(__float2bfloat16(a), __float2bfloat16(b));
  return r.u;
}
__device__ __forceinline__ float bu(unsigned short u) {
  return __uint_as_float(((unsigned)u) << 16);
}
__device__ __forceinline__ float silu_f(float x) {
  return x * __builtin_amdgcn_rcpf(1.f + __expf(-x));
}
__device__ __forceinline__ float sigm_f(float x) {
  return __builtin_amdgcn_rcpf(1.f + __expf(-x));
}

// ---------------- K1: LN1 + QKV (4 rows/block) + fused weight-prep (block 256) ----------------
__global__ __launch_bounds__(256) void k_ln1_qkv_prep(
    const float* __restrict__ feats, const float* __restrict__ g, const float* __restrict__ b,
    const float* __restrict__ qkv_w, float* __restrict__ xn, float* __restrict__ qkv,
    const float* __restrict__ ew1, const float* __restrict__ eb1,
    const float* __restrict__ ew2, const float* __restrict__ cw1,
    const float* __restrict__ eb2, const float* __restrict__ cb1,
    unsigned short* __restrict__ pw, float* __restrict__ b3p) {
  __shared__ float sh[64 * 64];
  const int t = threadIdx.x;
  if (blockIdx.x == 256) {
    float* wc = sh;
    for (int idx = t; idx < 4096; idx += 256) {
      const int r = idx >> 6, c = idx & 63;
      float s = 0.f;
#pragma unroll 8
      for (int k = 0; k < 64; ++k) s += ew2[r * 64 + k] * cw1[k * 64 + c];
      wc[idx] = s;
    }
    __syncthreads();
    for (int idx = t; idx < 12 * 512; idx += 256) {
      const int e = idx & 7, l = (idx >> 3) & 63, f = idx >> 9;
      const int l15 = l & 15, lg = l >> 4;
      float v;
      if (f < 4) {
        const int d = f * 16 + l15, k = lg * 8 + e;
        v = (k < 9) ? ew1[k * 64 + d] : (k == 9 ? eb1[d] : 0.f);
      } else {
        const int gq = f - 4, d = (gq >> 1) * 16 + l15, k = (gq & 1) * 32 + lg * 8 + e;
        v = wc[k * 64 + d];
      }
      pw[idx] = f2b(v);
    }
    if (t < 64) {
      float s = cb1[t];
#pragma unroll 8
      for (int k = 0; k < 64; ++k) s += eb2[k] * cw1[k * 64 + t];
      b3p[t] = s;
    }
    return;
  }
  const int r = t >> 6, lane = t & 63;
  const int i = blockIdx.x * 4 + r;
  float v = feats[i * D + lane];
  float s = v;
#pragma unroll
  for (int off = 32; off; off >>= 1) s += __shfl_xor(s, off);
  const float m = s * (1.0f / 64.0f);
  const float dv = v - m;
  float vs = dv * dv;
#pragma unroll
  for (int off = 32; off; off >>= 1) vs += __shfl_xor(vs, off);
  const float var = vs * (1.0f / 64.0f);
  const float xv = dv * rsqrtf(var + 1e-5f) * g[lane] + b[lane];
  xn[i * D + lane] = xv;
  float* xs = sh;  // [4][64]
  xs[r * 64 + lane] = xv;
  __syncthreads();
#pragma unroll
  for (int c = 0; c < 3; ++c) {
    const int col = lane + c * 64;
    float acc = 0.f;
#pragma unroll 8
    for (int k = 0; k < D; ++k) acc += xs[r * 64 + k] * qkv_w[k * 192 + col];
    qkv[i * 192 + col] = acc;
  }
}

// ---------------- K_scores: MFMA QK^T -> exp -> P (bf16) + l partials + fused PV partials ----
__global__ __launch_bounds__(256) void k_scores(
    const float* __restrict__ qkv, unsigned short* __restrict__ P,
    float* __restrict__ l_ws, float* __restrict__ pv_ws) {
  const int i0 = blockIdx.x * 64, j0 = blockIdx.y * 64, jb = blockIdx.y;
  const int t = threadIdx.x;
  const int lane = t & 63, h = t >> 6;
  const int l15 = lane & 15, lg = lane >> 4;
  const int r7 = l15 & 7;

  __shared__ __align__(16) unsigned short Qs[64 * 64];
  __shared__ __align__(16) unsigned short Ks[64 * 64];
  __shared__ __align__(16) unsigned short VTs[4 * 16 * 64];
  __shared__ __align__(16) unsigned short Ps[4 * 64 * 64];

  {
    const int si = t >> 2, q4 = t & 3;
    const int g0 = ((q4 * 2) ^ (si & 7)) * 8, g1 = ((q4 * 2 + 1) ^ (si & 7)) * 8;
    {
      const float* qr = &qkv[(i0 + si) * 192 + q4 * 16];
      float4 a0 = *(const float4*)(qr + 0), a1 = *(const float4*)(qr + 4);
      float4 a2 = *(const float4*)(qr + 8), a3 = *(const float4*)(qr + 12);
      *(uint4*)&Qs[si * 64 + g0] = make_uint4(
          pk2(a0.x * 0.125f, a0.y * 0.125f), pk2(a0.z * 0.125f, a0.w * 0.125f),
          pk2(a1.x * 0.125f, a1.y * 0.125f), pk2(a1.z * 0.125f, a1.w * 0.125f));
      *(uint4*)&Qs[si * 64 + g1] = make_uint4(
          pk2(a2.x * 0.125f, a2.y * 0.125f), pk2(a2.z * 0.125f, a2.w * 0.125f),
          pk2(a3.x * 0.125f, a3.y * 0.125f), pk2(a3.z * 0.125f, a3.w * 0.125f));
    }
    {
      const float* kr = &qkv[(j0 + si) * 192 + 64 + q4 * 16];
      float4 a0 = *(const float4*)(kr + 0), a1 = *(const float4*)(kr + 4);
      float4 a2 = *(const float4*)(kr + 8), a3 = *(const float4*)(kr + 12);
      *(uint4*)&Ks[si * 64 + g0] = make_uint4(pk2(a0.x, a0.y), pk2(a0.z, a0.w),
                                              pk2(a1.x, a1.y), pk2(a1.z, a1.w));
      *(uint4*)&Ks[si * 64 + g1] = make_uint4(pk2(a2.x, a2.y), pk2(a2.z, a2.w),
                                              pk2(a3.x, a3.y), pk2(a3.z, a3.w));
    }
    {
      const float* vr = &qkv[(j0 + si) * 192 + 128 + q4 * 16];
      float4 v0 = *(const float4*)(vr + 0), v1 = *(const float4*)(vr + 4);
      float4 v2 = *(const float4*)(vr + 8), v3 = *(const float4*)(vr + 12);
      float vv[16] = {v0.x, v0.y, v0.z, v0.w, v1.x, v1.y, v1.z, v1.w,
                      v2.x, v2.y, v2.z, v2.w, v3.x, v3.y, v3.z, v3.w};
      const int sj3 = si >> 3, sj7 = si & 7;
#pragma unroll
      for (int cc = 0; cc < 16; ++cc)
        VTs[q4 * 1024 + cc * 64 + ((sj3 ^ (cc & 7)) * 8) + sj7] = f2bc(vv[cc]);
    }
  }
  __syncthreads();

  const bf16x8 z8 = {0, 0, 0, 0, 0, 0, 0, 0};
  const int gk = ((h * 2 + (lg & 1)) ^ r7) * 8;
  bf16x8 qa[4], kb[4];
#pragma unroll
  for (int it = 0; it < 4; ++it) {
    qa[it] = *(const bf16x8*)&Qs[(it * 16 + l15) * 64 + gk];
    if (lg >= 2) qa[it] = z8;
    kb[it] = *(const bf16x8*)&Ks[(it * 16 + l15) * 64 + gk];
  }
  f32x4 acc[4][4];
#pragma unroll
  for (int it = 0; it < 4; ++it)
#pragma unroll
    for (int jt = 0; jt < 4; ++jt)
      acc[it][jt] = (f32x4){0.f, 0.f, 0.f, 0.f};
#pragma unroll
  for (int it = 0; it < 4; ++it)
#pragma unroll
    for (int jt = 0; jt < 4; ++jt)
      acc[it][jt] = __builtin_amdgcn_mfma_f32_16x16x32_bf16(qa[it], kb[jt], acc[it][jt], 0, 0, 0);

  float prow[4][4];
#pragma unroll
  for (int it = 0; it < 4; ++it)
#pragma unroll
    for (int rr = 0; rr < 4; ++rr) prow[it][rr] = 0.f;
#pragma unroll
  for (int it = 0; it < 4; ++it)
#pragma unroll
    for (int jt = 0; jt < 4; ++jt)
#pragma unroll
      for (int rr = 0; rr < 4; ++rr) {
        const float p = __expf(acc[it][jt][rr]);
        prow[it][rr] += p;
        const int irow = it * 16 + lg * 4 + rr;
        const int col = jt * 16 + l15;
        Ps[h * 4096 + irow * 64 + (((col >> 3) ^ (irow & 7)) * 8) + (col & 7)] = f2bc(p);
      }
#pragma unroll
  for (int it = 0; it < 4; ++it)
#pragma unroll
    for (int rr = 0; rr < 4; ++rr) {
      float s = prow[it][rr];
      s += __shfl_xor(s, 1); s += __shfl_xor(s, 2);
      s += __shfl_xor(s, 4); s += __shfl_xor(s, 8);
      if (l15 == 0)
        l_ws[h * 16384 + jb * 1024 + i0 + it * 16 + lg * 4 + rr] = s;
    }

  f32x4 av[4];
#pragma unroll
  for (int it = 0; it < 4; ++it) av[it] = (f32x4){0.f, 0.f, 0.f, 0.f};
#pragma unroll
  for (int ks = 0; ks < 2; ++ks) {
    const int gj = ((ks * 4 + lg) ^ r7) * 8;
    bf16x8 vb = *(const bf16x8*)&VTs[h * 1024 + l15 * 64 + gj];
#pragma unroll
    for (int it = 0; it < 4; ++it) {
      bf16x8 pa = *(const bf16x8*)&Ps[h * 4096 + (it * 16 + l15) * 64 + gj];
      av[it] = __builtin_amdgcn_mfma_f32_16x16x32_bf16(pa, vb, av[it], 0, 0, 0);
    }
  }
#pragma unroll
  for (int it = 0; it < 4; ++it)
#pragma unroll
    for (int rr = 0; rr < 4; ++rr)
      pv_ws[jb * 65536 + (i0 + it * 16 + lg * 4 + rr) * 64 + h * 16 + l15] = av[it][rr];

  {
    const int ir = t & 63;
    unsigned short* pg = &P[h * 1048576 + (i0 + ir) * 1024 + j0];
#pragma unroll
    for (int gg = 0; gg < 8; ++gg)
      *(uint4*)&pg[gg * 8] = *(const uint4*)&Ps[h * 4096 + ir * 64 + ((gg ^ (ir & 7)) * 8)];
  }
}

// ---------------- K_meanattn: ma[i][j] = 0.25*sum_h P_h[i][j]/l_h[i] (bf16) ----------
__global__ __launch_bounds__(256) void k_meanattn(
    const unsigned short* P, const float* __restrict__ l_ws, unsigned short* ma) {
  const int i0 = blockIdx.x * 64, j0 = blockIdx.y * 64;
  const int t = threadIdx.x;
  __shared__ float invl[4][64];
  {
    const int h = t >> 6, r = t & 63;
    float s = 0.f;
#pragma unroll
    for (int jt = 0; jt < 16; ++jt) s += l_ws[h * 16384 + jt * 1024 + i0 + r];
    invl[h][r] = 0.25f * __builtin_amdgcn_rcpf(s);
  }
  __syncthreads();
  {
    const int r = t >> 2, cg = t & 3;
    float v[16];
#pragma unroll
    for (int k = 0; k < 16; ++k) v[k] = 0.f;
#pragma unroll
    for (int h = 0; h < 4; ++h) {
      const unsigned short* pr = &P[h * 1048576 + (i0 + r) * 1024 + j0 + cg * 16];
      uint4 a = *(const uint4*)pr;
      uint4 b2 = *(const uint4*)(pr + 8);
      const float sh = invl[h][r];
      unsigned uu[8] = {a.x, a.y, a.z, a.w, b2.x, b2.y, b2.z, b2.w};
#pragma unroll
      for (int q = 0; q < 8; ++q) {
        v[q * 2 + 0] += sh * bu((unsigned short)(uu[q] & 0xffffu));
        v[q * 2 + 1] += sh * bu((unsigned short)(uu[q] >> 16));
      }
    }
    unsigned out[8];
#pragma unroll
    for (int q = 0; q < 8; ++q) out[q] = pk2(v[2 * q], v[2 * q + 1]);
    unsigned short* mr = &ma[(i0 + r) * 1024 + j0 + cg * 16];
    *(uint4*)mr = make_uint4(out[0], out[1], out[2], out[3]);
    *(uint4*)(mr + 8) = make_uint4(out[4], out[5], out[6], out[7]);
  }
}

// ---------------- K3: msg combine + out-proj + residual + LN2 + FFN + gate ----------------
__global__ __launch_bounds__(256) void k_ffn_gate(
    const float* __restrict__ pv_ws, const float* __restrict__ l_ws,
    const float* __restrict__ xn,
    const float* __restrict__ out_w, const float* __restrict__ out_b,
    const float* __restrict__ ln2_g, const float* __restrict__ ln2_b,
    const float* __restrict__ fw1, const float* __restrict__ fb1,
    const float* __restrict__ fw2, const float* __restrict__ fb2,
    const float* __restrict__ gw1, const float* __restrict__ gb1,
    const float* __restrict__ gw2, const float* __restrict__ gb2,
    float* __restrict__ xout, float* __restrict__ gate) {
  const int i = blockIdx.x, t = threadIdx.x;
  __shared__ float msgv[64], xs[64], x1s[64], hs[256];
  if (t < 64) {
    float ls = 0.f;
#pragma unroll
    for (int jt = 0; jt < 16; ++jt) ls += l_ws[(t >> 4) * 16384 + jt * 1024 + i];
    const float invh = __builtin_amdgcn_rcpf(ls);
    float s = 0.f;
#pragma unroll
    for (int jt = 0; jt < 16; ++jt) s += pv_ws[jt * 65536 + i * 64 + t];
    msgv[t] = s * invh;
  }
  __syncthreads();
  if (t < 64) {
    float o = out_b[t];
#pragma unroll 8
    for (int k = 0; k < 64; ++k) o += msgv[k] * out_w[k * 64 + t];
    const float v = xn[i * 64 + t] + o;
    x1s[t] = v;
    float s = v;
#pragma unroll
    for (int off = 32; off; off >>= 1) s += __shfl_xor(s, off);
    const float m = s * (1.f / 64.f);
    const float dv = v - m;
    float vs = dv * dv;
#pragma unroll
    for (int off = 32; off; off >>= 1) vs += __shfl_xor(vs, off);
    xs[t] = dv * rsqrtf(vs * (1.f / 64.f) + 1e-5f) * ln2_g[t] + ln2_b[t];
  }
  __syncthreads();
  float a = fb1[t];
#pragma unroll 8
  for (int k = 0; k < 64; ++k) a += xs[k] * fw1[k * 256 + t];
  const float ge = 0.5f * a * (1.f + erff(a * 0.70710678118f));
  hs[t] = ge;
  __syncthreads();
  if (t < 64) {
    float o = fb2[t];
#pragma unroll 8
    for (int k = 0; k < 256; ++k) o += hs[k] * fw2[k * 64 + t];
    const float xo = x1s[t] + o;
    xout[i * 64 + t] = xo;
    xs[t] = xo;
  }
  __syncthreads();
  if (t < 64) {
    float a2 = gb1[t];
#pragma unroll 8
    for (int k = 0; k < 64; ++k) a2 += xs[k] * gw1[k * 64 + t];
    const float sg = a2 * sigm_f(a2);
    float pp = sg * gw2[t];
#pragma unroll
    for (int off = 32; off; off >>= 1) pp += __shfl_xor(pp, off);
    if (t == 0) gate[i] = sigm_f(pp + gb2[0]);
  }
}

// ---------------- K4: symmetric-pair MFMA, 1024 exactly-balanced blocks ------
// Work units: off-diag tile-pair (ti<tj) = 32 wave-chunks -> TWO half-blocks
// (h=0: dgn 0-15, h=1: dgn 16-31); diag tile = 16 wave-chunks -> ONE block
// (dgn 1-16, dgn=16 half-masked). 992 + 32 = 1024 uniform blocks = 4/CU,
// all co-resident, single dispatch round, zero tail.
// Slab ownership (no collisions): off-diag di rows -> slab 2*tj+h, dj rows ->
// slab 2*ti+h; diag rows -> slab 2*ti (row-block ti*32 unused there otherwise).
__global__ __launch_bounds__(256, 2) void k_pair(
    const float* __restrict__ coors, const unsigned short* __restrict__ ma,
    const unsigned short* __restrict__ pw,
    const float* __restrict__ b3p, const float* __restrict__ c2g,
    const float* __restrict__ cb2, float* __restrict__ partial) {
  const int b = blockIdx.x;
  int ti, tj, h;
  bool diag;
  if (b < 992) {
    const int q = b >> 1;
    h = b & 1;
    int bb = q;
    ti = 0;
    while (bb >= 31 - ti) { bb -= 31 - ti; ++ti; }
    tj = ti + 1 + bb;
    diag = false;
  } else {
    ti = tj = b - 992;
    h = 0;
    diag = true;
  }

  const int t = threadIdx.x;
  const int w = t >> 6;
  const int lane = t & 63;
  const int l15 = lane & 15;
  const int lg = lane >> 4;

  __shared__ __align__(16) unsigned short buf[4][32][64];
  __shared__ float4 relA[4][32], relB[4][32];
  __shared__ float di[4][32][3], dj[4][32][3];

  bf16x8 wf[12];
#pragma unroll
  for (int f = 0; f < 12; ++f)
    wf[f] = *(const bf16x8*)&pw[(f * 64 + lane) * 8];

  float b3v[16], c2v[16];
#pragma unroll
  for (int mt = 0; mt < 4; ++mt)
#pragma unroll
    for (int r = 0; r < 4; ++r) {
      const int d = mt * 16 + lg * 4 + r;
      b3v[mt * 4 + r] = b3p[d];
      c2v[mt * 4 + r] = c2g[d];
    }
  const float cb2q = cb2[0];  // ma carries 0.25/l
  if (lane < 32) {
    const int j = lane;
#pragma unroll
    for (int k2 = 0; k2 < 3; ++k2) { di[w][j][k2] = 0.f; dj[w][j][k2] = 0.f; }
    unsigned short* rp = &buf[w][j][0];
    const uint4 z4 = make_uint4(0, 0, 0, 0);
    *(uint4*)&rp[(1 ^ (j & 7)) * 8] = z4;
    *(uint4*)&rp[(2 ^ (j & 7)) * 8] = z4;
    *(uint4*)&rp[(3 ^ (j & 7)) * 8] = z4;
  }

  f32x4 acc[4][2];

  for (int c = 0; c < 4; ++c) {
    const int dgn = diag ? (c * 4 + w + 1) : (h * 16 + c * 4 + w);
    // ---- enc + rel + both ma factors ----
    {
      const int p = lane & 31;
      const int hhalf = lane >> 5;
      const int ig = ti * 32 + p;
      const int jj = (p + dgn) & 31;
      const int jg = tj * 32 + jj;
      const float rx = coors[ig * 3 + 0] - coors[jg * 3 + 0];
      const float ry = coors[ig * 3 + 1] - coors[jg * 3 + 1];
      const float rz = coors[ig * 3 + 2] - coors[jg * 3 + 2];
      const float rd = rx * rx + ry * ry + rz * rz;
      unsigned short* rp = &buf[w][p][0];
      if (hhalf == 0) {
        float mi = bu(ma[ig * 1024 + jg]);
        float mj = bu(ma[jg * 1024 + ig]);
        if (diag && dgn == 16 && p >= 16) { mi = 0.f; mj = 0.f; }
        relA[w][p] = make_float4(mi * rx, mi * ry, mi * rz, 0.f);
        relB[w][p] = make_float4(mj * rx, mj * ry, mj * rz, 0.f);
        *(uint2*)&rp[(0 ^ (p & 7)) * 8] =
            make_uint2(pk2(__sinf(rd), __sinf(rd * 0.5f)),
                       pk2(__sinf(rd * 0.25f), __sinf(rd * 0.125f)));
        *(unsigned*)&rp[(1 ^ (p & 7)) * 8] = pk2(rd, 1.0f);
      } else {
        *(uint2*)&rp[((0 ^ (p & 7)) * 8) + 4] =
            make_uint2(pk2(__cosf(rd), __cosf(rd * 0.5f)),
                       pk2(__cosf(rd * 0.25f), __cosf(rd * 0.125f)));
      }
    }

    // GEMM1: h1T = W1T @ encT (K=32, bias via k=9)
#pragma unroll
    for (int mt = 0; mt < 4; ++mt)
#pragma unroll
      for (int nt = 0; nt < 2; ++nt)
        acc[mt][nt] = (f32x4){0.f, 0.f, 0.f, 0.f};
    {
      const int j0 = l15, j1 = 16 + l15;
      bf16x8 bf0 = *(const bf16x8*)&buf[w][j0][(lg ^ (j0 & 7)) * 8];
      bf16x8 bf1 = *(const bf16x8*)&buf[w][j1][(lg ^ (j1 & 7)) * 8];
#pragma unroll
      for (int mt = 0; mt < 4; ++mt) {
        acc[mt][0] = __builtin_amdgcn_mfma_f32_16x16x32_bf16(wf[mt], bf0, acc[mt][0], 0, 0, 0);
        acc[mt][1] = __builtin_amdgcn_mfma_f32_16x16x32_bf16(wf[mt], bf1, acc[mt][1], 0, 0, 0);
      }
    }
    // silu -> same slot (aliases dead enc; W1T rows k>=10 are zero)
#pragma unroll
    for (int mt = 0; mt < 4; ++mt)
#pragma unroll
      for (int nt = 0; nt < 2; ++nt) {
        const f32x4 a = acc[mt][nt];
        const unsigned lo = pk2(silu_f(a[0]), silu_f(a[1]));
        const unsigned hi = pk2(silu_f(a[2]), silu_f(a[3]));
        const int j = nt * 16 + l15;
        const int g = mt * 2 + (lg >> 1);
        *(uint2*)&buf[w][j][((g ^ (j & 7)) * 8) + (lg & 1) * 4] = make_uint2(lo, hi);
      }

    // merged GEMM: h2T = Wc^T @ h1T (K=64)
#pragma unroll
    for (int mt = 0; mt < 4; ++mt)
#pragma unroll
      for (int nt = 0; nt < 2; ++nt)
        acc[mt][nt] = (f32x4){b3v[mt * 4 + 0], b3v[mt * 4 + 1], b3v[mt * 4 + 2], b3v[mt * 4 + 3]};
#pragma unroll
    for (int ks = 0; ks < 2; ++ks) {
      const int gi = ks * 4 + lg;
      const int j0 = l15, j1 = 16 + l15;
      bf16x8 bf0 = *(const bf16x8*)&buf[w][j0][(gi ^ (j0 & 7)) * 8];
      bf16x8 bf1 = *(const bf16x8*)&buf[w][j1][(gi ^ (j1 & 7)) * 8];
#pragma unroll
      for (int mt = 0; mt < 4; ++mt) {
        acc[mt][0] = __builtin_amdgcn_mfma_f32_16x16x32_bf16(wf[4 + mt * 2 + ks], bf0, acc[mt][0], 0, 0, 0);
        acc[mt][1] = __builtin_amdgcn_mfma_f32_16x16x32_bf16(wf[4 + mt * 2 + ks], bf1, acc[mt][1], 0, 0, 0);
      }
    }

    // epilogue: full cw per col via lg-reduce, then dual accumulation
#pragma unroll
    for (int nt = 0; nt < 2; ++nt) {
      float cwp = cb2q;
#pragma unroll
      for (int mt = 0; mt < 4; ++mt) {
        const f32x4 a = acc[mt][nt];
#pragma unroll
        for (int r = 0; r < 4; ++r) cwp += silu_f(a[r]) * c2v[mt * 4 + r];
      }
      cwp += __shfl_xor(cwp, 16);
      cwp += __shfl_xor(cwp, 32);
      if (lg == 0) {
        const int p = nt * 16 + l15;
        const int jj = (p + dgn) & 31;
        const float4 rA = relA[w][p];
        const float4 rB = relB[w][p];
        di[w][p][0] += cwp * rA.x; di[w][p][1] += cwp * rA.y; di[w][p][2] += cwp * rA.z;
        dj[w][jj][0] -= cwp * rB.x; dj[w][jj][1] -= cwp * rB.y; dj[w][jj][2] -= cwp * rB.z;
      }
    }
  }

  __syncthreads();
  if (!diag) {
    if (t < 96) {
      const int p = t / 3, k = t % 3;
      const float s = di[0][p][k] + di[1][p][k] + di[2][p][k] + di[3][p][k];
      partial[(tj * 2 + h) * 3072 + (ti * 32 + p) * 3 + k] = s;
    } else if (t < 192) {
      const int u = t - 96, q2 = u / 3, k = u % 3;
      const float s = dj[0][q2][k] + dj[1][q2][k] + dj[2][q2][k] + dj[3][q2][k];
      partial[(ti * 2 + h) * 3072 + (tj * 32 + q2) * 3 + k] = s;
    }
  } else {
    if (t < 96) {
      const int p = t / 3, k = t % 3;
      const float s = di[0][p][k] + di[1][p][k] + di[2][p][k] + di[3][p][k]
                    + dj[0][p][k] + dj[1][p][k] + dj[2][p][k] + dj[3][p][k];
      partial[(ti * 2) * 3072 + (ti * 32 + p) * 3 + k] = s;
    }
  }
}

// ---------------- K_finalize: reduce 64 slabs, apply gate ----------------
__global__ __launch_bounds__(256) void k_finalize(
    const float* __restrict__ coors, const float* __restrict__ partial,
    const float* __restrict__ gate, float* __restrict__ outc) {
  const int idx = blockIdx.x * 256 + threadIdx.x;  // 0..3071 = i*3+k
  if (idx < 3072) {
    float s = 0.f;
#pragma unroll
    for (int sl = 0; sl < 64; ++sl) s += partial[sl * 3072 + idx];
    outc[idx] = coors[idx] + s * gate[idx / 3];
  }
}

extern "C" void kernel_launch(void* const* d_in, const int* in_sizes, int n_in,
                              void* d_out, int out_size, void* d_ws, size_t ws_size,
                              hipStream_t stream) {
  const float* feats = (const float*)d_in[0];
  const float* coors = (const float*)d_in[1];
  const float* qkv_w = (const float*)d_in[2];
  const float* out_w = (const float*)d_in[3];
  const float* out_b = (const float*)d_in[4];
  const float* ew1 = (const float*)d_in[5];
  const float* eb1 = (const float*)d_in[6];
  const float* ew2 = (const float*)d_in[7];
  const float* eb2 = (const float*)d_in[8];
  const float* cw1 = (const float*)d_in[9];
  const float* cb1 = (const float*)d_in[10];
  const float* cw2 = (const float*)d_in[11];
  const float* cb2 = (const float*)d_in[12];
  const float* gw1 = (const float*)d_in[13];
  const float* gb1 = (const float*)d_in[14];
  const float* gw2 = (const float*)d_in[15];
  const float* gb2 = (const float*)d_in[16];
  const float* ln1_g = (const float*)d_in[17];
  const float* ln1_b = (const float*)d_in[18];
  const float* ln2_g = (const float*)d_in[19];
  const float* ln2_b = (const float*)d_in[20];
  const float* fw1 = (const float*)d_in[21];
  const float* fb1 = (const float*)d_in[22];
  const float* fw2 = (const float*)d_in[23];
  const float* fb2 = (const float*)d_in[24];

  float* ws = (float*)d_ws;
  float* xn = ws;                                        // 65536
  float* qkv = ws + 65536;                               // 196608
  float* gate = ws + 262144;                             // 1024
  unsigned short* pw = (unsigned short*)(ws + 263168);   // 6144 ushorts = 3072 floats
  float* b3p = ws + 266240;                              // 64
  float* l_ws = ws + 266304;                             // 65536
  float* pv_ws = ws + 331840;                            // 1048576
  float* partial = ws + 1380416;                         // 196608 (64 slabs x 1024 x 3)
  unsigned short* P = (unsigned short*)(ws + 1577024);   // 4M ushorts = 2097152 floats
  unsigned short* ma = P;                                // aliases P_0 plane

  float* xout = (float*)d_out;
  float* coorout = xout + 65536;

  hipLaunchKernelGGL(k_ln1_qkv_prep, dim3(257), dim3(256), 0, stream,
                     feats, ln1_g, ln1_b, qkv_w, xn, qkv,
                     ew1, eb1, ew2, cw1, eb2, cb1, pw, b3p);
  hipLaunchKernelGGL(k_scores, dim3(16, 16), dim3(256), 0, stream, qkv, P, l_ws, pv_ws);
  hipLaunchKernelGGL(k_meanattn, dim3(16, 16), dim3(256), 0, stream, P, l_ws, ma);
  hipLaunchKernelGGL(k_ffn_gate, dim3(N), dim3(256), 0, stream, pv_ws, l_ws, xn,
                     out_w, out_b, ln2_g, ln2_b,
                     fw1, fb1, fw2, fb2, gw1, gb1, gw2, gb2, xout, gate);
  hipLaunchKernelGGL(k_pair, dim3(1024), dim3(256), 0, stream, coors, ma, pw,
                     b3p, cw2, cb2, partial);
  hipLaunchKernelGGL(k_finalize, dim3(12), dim3(256), 0, stream, coors, partial, gate, coorout);
}

// Round 14
// 104.966 us; speedup vs baseline: 1.0566x; 1.0566x over previous
//
#include <hip/hip_runtime.h>
#include <hip/hip_bf16.h>

#define N 1024
#define D 64

typedef __attribute__((ext_vector_type(8))) short bf16x8;
typedef __attribute__((ext_vector_type(4))) float f32x4;

__device__ __forceinline__ unsigned short f2b(float v) {
  unsigned u = __float_as_uint(v);
  u += 0x7fffu + ((u >> 16) & 1u);
  return (unsigned short)(u >> 16);
}
__device__ __forceinline__ unsigned short f2bc(float v) {
  union { __hip_bfloat16 h; unsigned short u; } r;
  r.h = __float2bfloat16(v);
  return r.u;
}
__device__ __forceinline__ unsigned pk2(float a, float b) {
  union { __hip_bfloat162 h; unsigned u; } r;
  r.h = __hip_bfloat162(__float2bfloat16(a), __float2bfloat16(b));
  return r.u;
}
__device__ __forceinline__ float bu(unsigned short u) {
  return __uint_as_float(((unsigned)u) << 16);
}
__device__ __forceinline__ float silu_f(float x) {
  return x * __builtin_amdgcn_rcpf(1.f + __expf(-x));
}
__device__ __forceinline__ float sigm_f(float x) {
  return __builtin_amdgcn_rcpf(1.f + __expf(-x));
}

// ---------------- K1: LN1 + QKV (4 rows/block) + fused weight-prep (block 256) ----------------
__global__ __launch_bounds__(256) void k_ln1_qkv_prep(
    const float* __restrict__ feats, const float* __restrict__ g, const float* __restrict__ b,
    const float* __restrict__ qkv_w, float* __restrict__ xn, float* __restrict__ qkv,
    const float* __restrict__ ew1, const float* __restrict__ eb1,
    const float* __restrict__ ew2, const float* __restrict__ cw1,
    const float* __restrict__ eb2, const float* __restrict__ cb1,
    unsigned short* __restrict__ pw, float* __restrict__ b3p) {
  __shared__ float sh[64 * 64];
  const int t = threadIdx.x;
  if (blockIdx.x == 256) {
    float* wc = sh;
    for (int idx = t; idx < 4096; idx += 256) {
      const int r = idx >> 6, c = idx & 63;
      float s = 0.f;
#pragma unroll 8
      for (int k = 0; k < 64; ++k) s += ew2[r * 64 + k] * cw1[k * 64 + c];
      wc[idx] = s;
    }
    __syncthreads();
    for (int idx = t; idx < 12 * 512; idx += 256) {
      const int e = idx & 7, l = (idx >> 3) & 63, f = idx >> 9;
      const int l15 = l & 15, lg = l >> 4;
      float v;
      if (f < 4) {
        const int d = f * 16 + l15, k = lg * 8 + e;
        v = (k < 9) ? ew1[k * 64 + d] : (k == 9 ? eb1[d] : 0.f);
      } else {
        const int gq = f - 4, d = (gq >> 1) * 16 + l15, k = (gq & 1) * 32 + lg * 8 + e;
        v = wc[k * 64 + d];
      }
      pw[idx] = f2b(v);
    }
    if (t < 64) {
      float s = cb1[t];
#pragma unroll 8
      for (int k = 0; k < 64; ++k) s += eb2[k] * cw1[k * 64 + t];
      b3p[t] = s;
    }
    return;
  }
  const int r = t >> 6, lane = t & 63;
  const int i = blockIdx.x * 4 + r;
  float v = feats[i * D + lane];
  float s = v;
#pragma unroll
  for (int off = 32; off; off >>= 1) s += __shfl_xor(s, off);
  const float m = s * (1.0f / 64.0f);
  const float dv = v - m;
  float vs = dv * dv;
#pragma unroll
  for (int off = 32; off; off >>= 1) vs += __shfl_xor(vs, off);
  const float var = vs * (1.0f / 64.0f);
  const float xv = dv * rsqrtf(var + 1e-5f) * g[lane] + b[lane];
  xn[i * D + lane] = xv;
  float* xs = sh;  // [4][64]
  xs[r * 64 + lane] = xv;
  __syncthreads();
#pragma unroll
  for (int c = 0; c < 3; ++c) {
    const int col = lane + c * 64;
    float acc = 0.f;
#pragma unroll 8
    for (int k = 0; k < D; ++k) acc += xs[r * 64 + k] * qkv_w[k * 192 + col];
    qkv[i * 192 + col] = acc;
  }
}

// ---------------- K_scores: MFMA QK^T -> exp -> P (bf16) + l partials + fused PV partials ----
__global__ __launch_bounds__(256) void k_scores(
    const float* __restrict__ qkv, unsigned short* __restrict__ P,
    float* __restrict__ l_ws, float* __restrict__ pv_ws) {
  const int i0 = blockIdx.x * 64, j0 = blockIdx.y * 64, jb = blockIdx.y;
  const int t = threadIdx.x;
  const int lane = t & 63, h = t >> 6;
  const int l15 = lane & 15, lg = lane >> 4;
  const int r7 = l15 & 7;

  __shared__ __align__(16) unsigned short Qs[64 * 64];
  __shared__ __align__(16) unsigned short Ks[64 * 64];
  __shared__ __align__(16) unsigned short VTs[4 * 16 * 64];
  __shared__ __align__(16) unsigned short Ps[4 * 64 * 64];

  {
    const int si = t >> 2, q4 = t & 3;
    const int g0 = ((q4 * 2) ^ (si & 7)) * 8, g1 = ((q4 * 2 + 1) ^ (si & 7)) * 8;
    {
      const float* qr = &qkv[(i0 + si) * 192 + q4 * 16];
      float4 a0 = *(const float4*)(qr + 0), a1 = *(const float4*)(qr + 4);
      float4 a2 = *(const float4*)(qr + 8), a3 = *(const float4*)(qr + 12);
      *(uint4*)&Qs[si * 64 + g0] = make_uint4(
          pk2(a0.x * 0.125f, a0.y * 0.125f), pk2(a0.z * 0.125f, a0.w * 0.125f),
          pk2(a1.x * 0.125f, a1.y * 0.125f), pk2(a1.z * 0.125f, a1.w * 0.125f));
      *(uint4*)&Qs[si * 64 + g1] = make_uint4(
          pk2(a2.x * 0.125f, a2.y * 0.125f), pk2(a2.z * 0.125f, a2.w * 0.125f),
          pk2(a3.x * 0.125f, a3.y * 0.125f), pk2(a3.z * 0.125f, a3.w * 0.125f));
    }
    {
      const float* kr = &qkv[(j0 + si) * 192 + 64 + q4 * 16];
      float4 a0 = *(const float4*)(kr + 0), a1 = *(const float4*)(kr + 4);
      float4 a2 = *(const float4*)(kr + 8), a3 = *(const float4*)(kr + 12);
      *(uint4*)&Ks[si * 64 + g0] = make_uint4(pk2(a0.x, a0.y), pk2(a0.z, a0.w),
                                              pk2(a1.x, a1.y), pk2(a1.z, a1.w));
      *(uint4*)&Ks[si * 64 + g1] = make_uint4(pk2(a2.x, a2.y), pk2(a2.z, a2.w),
                                              pk2(a3.x, a3.y), pk2(a3.z, a3.w));
    }
    {
      const float* vr = &qkv[(j0 + si) * 192 + 128 + q4 * 16];
      float4 v0 = *(const float4*)(vr + 0), v1 = *(const float4*)(vr + 4);
      float4 v2 = *(const float4*)(vr + 8), v3 = *(const float4*)(vr + 12);
      float vv[16] = {v0.x, v0.y, v0.z, v0.w, v1.x, v1.y, v1.z, v1.w,
                      v2.x, v2.y, v2.z, v2.w, v3.x, v3.y, v3.z, v3.w};
      const int sj3 = si >> 3, sj7 = si & 7;
#pragma unroll
      for (int cc = 0; cc < 16; ++cc)
        VTs[q4 * 1024 + cc * 64 + ((sj3 ^ (cc & 7)) * 8) + sj7] = f2bc(vv[cc]);
    }
  }
  __syncthreads();

  const bf16x8 z8 = {0, 0, 0, 0, 0, 0, 0, 0};
  const int gk = ((h * 2 + (lg & 1)) ^ r7) * 8;
  bf16x8 qa[4], kb[4];
#pragma unroll
  for (int it = 0; it < 4; ++it) {
    qa[it] = *(const bf16x8*)&Qs[(it * 16 + l15) * 64 + gk];
    if (lg >= 2) qa[it] = z8;
    kb[it] = *(const bf16x8*)&Ks[(it * 16 + l15) * 64 + gk];
  }
  f32x4 acc[4][4];
#pragma unroll
  for (int it = 0; it < 4; ++it)
#pragma unroll
    for (int jt = 0; jt < 4; ++jt)
      acc[it][jt] = (f32x4){0.f, 0.f, 0.f, 0.f};
#pragma unroll
  for (int it = 0; it < 4; ++it)
#pragma unroll
    for (int jt = 0; jt < 4; ++jt)
      acc[it][jt] = __builtin_amdgcn_mfma_f32_16x16x32_bf16(qa[it], kb[jt], acc[it][jt], 0, 0, 0);

  float prow[4][4];
#pragma unroll
  for (int it = 0; it < 4; ++it)
#pragma unroll
    for (int rr = 0; rr < 4; ++rr) prow[it][rr] = 0.f;
#pragma unroll
  for (int it = 0; it < 4; ++it)
#pragma unroll
    for (int jt = 0; jt < 4; ++jt)
#pragma unroll
      for (int rr = 0; rr < 4; ++rr) {
        const float p = __expf(acc[it][jt][rr]);
        prow[it][rr] += p;
        const int irow = it * 16 + lg * 4 + rr;
        const int col = jt * 16 + l15;
        Ps[h * 4096 + irow * 64 + (((col >> 3) ^ (irow & 7)) * 8) + (col & 7)] = f2bc(p);
      }
#pragma unroll
  for (int it = 0; it < 4; ++it)
#pragma unroll
    for (int rr = 0; rr < 4; ++rr) {
      float s = prow[it][rr];
      s += __shfl_xor(s, 1); s += __shfl_xor(s, 2);
      s += __shfl_xor(s, 4); s += __shfl_xor(s, 8);
      if (l15 == 0)
        l_ws[h * 16384 + jb * 1024 + i0 + it * 16 + lg * 4 + rr] = s;
    }

  f32x4 av[4];
#pragma unroll
  for (int it = 0; it < 4; ++it) av[it] = (f32x4){0.f, 0.f, 0.f, 0.f};
#pragma unroll
  for (int ks = 0; ks < 2; ++ks) {
    const int gj = ((ks * 4 + lg) ^ r7) * 8;
    bf16x8 vb = *(const bf16x8*)&VTs[h * 1024 + l15 * 64 + gj];
#pragma unroll
    for (int it = 0; it < 4; ++it) {
      bf16x8 pa = *(const bf16x8*)&Ps[h * 4096 + (it * 16 + l15) * 64 + gj];
      av[it] = __builtin_amdgcn_mfma_f32_16x16x32_bf16(pa, vb, av[it], 0, 0, 0);
    }
  }
#pragma unroll
  for (int it = 0; it < 4; ++it)
#pragma unroll
    for (int rr = 0; rr < 4; ++rr)
      pv_ws[jb * 65536 + (i0 + it * 16 + lg * 4 + rr) * 64 + h * 16 + l15] = av[it][rr];

  {
    const int ir = t & 63;
    unsigned short* pg = &P[h * 1048576 + (i0 + ir) * 1024 + j0];
#pragma unroll
    for (int gg = 0; gg < 8; ++gg)
      *(uint4*)&pg[gg * 8] = *(const uint4*)&Ps[h * 4096 + ir * 64 + ((gg ^ (ir & 7)) * 8)];
  }
}

// ---------------- K_meanattn: ma[i][j] = 0.25*sum_h P_h[i][j]/l_h[i] (bf16) ----------
__global__ __launch_bounds__(256) void k_meanattn(
    const unsigned short* P, const float* __restrict__ l_ws, unsigned short* ma) {
  const int i0 = blockIdx.x * 64, j0 = blockIdx.y * 64;
  const int t = threadIdx.x;
  __shared__ float invl[4][64];
  {
    const int h = t >> 6, r = t & 63;
    float s = 0.f;
#pragma unroll
    for (int jt = 0; jt < 16; ++jt) s += l_ws[h * 16384 + jt * 1024 + i0 + r];
    invl[h][r] = 0.25f * __builtin_amdgcn_rcpf(s);
  }
  __syncthreads();
  {
    const int r = t >> 2, cg = t & 3;
    float v[16];
#pragma unroll
    for (int k = 0; k < 16; ++k) v[k] = 0.f;
#pragma unroll
    for (int h = 0; h < 4; ++h) {
      const unsigned short* pr = &P[h * 1048576 + (i0 + r) * 1024 + j0 + cg * 16];
      uint4 a = *(const uint4*)pr;
      uint4 b2 = *(const uint4*)(pr + 8);
      const float sh = invl[h][r];
      unsigned uu[8] = {a.x, a.y, a.z, a.w, b2.x, b2.y, b2.z, b2.w};
#pragma unroll
      for (int q = 0; q < 8; ++q) {
        v[q * 2 + 0] += sh * bu((unsigned short)(uu[q] & 0xffffu));
        v[q * 2 + 1] += sh * bu((unsigned short)(uu[q] >> 16));
      }
    }
    unsigned out[8];
#pragma unroll
    for (int q = 0; q < 8; ++q) out[q] = pk2(v[2 * q], v[2 * q + 1]);
    unsigned short* mr = &ma[(i0 + r) * 1024 + j0 + cg * 16];
    *(uint4*)mr = make_uint4(out[0], out[1], out[2], out[3]);
    *(uint4*)(mr + 8) = make_uint4(out[4], out[5], out[6], out[7]);
  }
}

// ---------------- K3: msg combine + out-proj + residual + LN2 + FFN + gate ----------------
__global__ __launch_bounds__(256) void k_ffn_gate(
    const float* __restrict__ pv_ws, const float* __restrict__ l_ws,
    const float* __restrict__ xn,
    const float* __restrict__ out_w, const float* __restrict__ out_b,
    const float* __restrict__ ln2_g, const float* __restrict__ ln2_b,
    const float* __restrict__ fw1, const float* __restrict__ fb1,
    const float* __restrict__ fw2, const float* __restrict__ fb2,
    const float* __restrict__ gw1, const float* __restrict__ gb1,
    const float* __restrict__ gw2, const float* __restrict__ gb2,
    float* __restrict__ xout, float* __restrict__ gate) {
  const int i = blockIdx.x, t = threadIdx.x;
  __shared__ float msgv[64], xs[64], x1s[64], hs[256];
  if (t < 64) {
    float ls = 0.f;
#pragma unroll
    for (int jt = 0; jt < 16; ++jt) ls += l_ws[(t >> 4) * 16384 + jt * 1024 + i];
    const float invh = __builtin_amdgcn_rcpf(ls);
    float s = 0.f;
#pragma unroll
    for (int jt = 0; jt < 16; ++jt) s += pv_ws[jt * 65536 + i * 64 + t];
    msgv[t] = s * invh;
  }
  __syncthreads();
  if (t < 64) {
    float o = out_b[t];
#pragma unroll 8
    for (int k = 0; k < 64; ++k) o += msgv[k] * out_w[k * 64 + t];
    const float v = xn[i * 64 + t] + o;
    x1s[t] = v;
    float s = v;
#pragma unroll
    for (int off = 32; off; off >>= 1) s += __shfl_xor(s, off);
    const float m = s * (1.f / 64.f);
    const float dv = v - m;
    float vs = dv * dv;
#pragma unroll
    for (int off = 32; off; off >>= 1) vs += __shfl_xor(vs, off);
    xs[t] = dv * rsqrtf(vs * (1.f / 64.f) + 1e-5f) * ln2_g[t] + ln2_b[t];
  }
  __syncthreads();
  float a = fb1[t];
#pragma unroll 8
  for (int k = 0; k < 64; ++k) a += xs[k] * fw1[k * 256 + t];
  const float ge = 0.5f * a * (1.f + erff(a * 0.70710678118f));
  hs[t] = ge;
  __syncthreads();
  if (t < 64) {
    float o = fb2[t];
#pragma unroll 8
    for (int k = 0; k < 256; ++k) o += hs[k] * fw2[k * 64 + t];
    const float xo = x1s[t] + o;
    xout[i * 64 + t] = xo;
    xs[t] = xo;
  }
  __syncthreads();
  if (t < 64) {
    float a2 = gb1[t];
#pragma unroll 8
    for (int k = 0; k < 64; ++k) a2 += xs[k] * gw1[k * 64 + t];
    const float sg = a2 * sigm_f(a2);
    float pp = sg * gw2[t];
#pragma unroll
    for (int off = 32; off; off >>= 1) pp += __shfl_xor(pp, off);
    if (t == 0) gate[i] = sigm_f(pp + gb2[0]);
  }
}

// ---------------- K4: symmetric-pair MFMA, balanced 1024 blocks, 2-chunk ILP ------
// Same work decomposition as R13 (992 off-diag half-blocks + 32 diag blocks).
// NEW: each wave processes TWO independent chunks (s=0,1) per iteration with
// interleaved phases -> 2x independent LDS/MFMA ops in flight per wave, halving
// the serial enc->G1->silu->G2 latency chain stall (R12: VALUBusy 35%).
__global__ __launch_bounds__(256) void k_pair(
    const float* __restrict__ coors, const unsigned short* __restrict__ ma,
    const unsigned short* __restrict__ pw,
    const float* __restrict__ b3p, const float* __restrict__ c2g,
    const float* __restrict__ cb2, float* __restrict__ partial) {
  const int b = blockIdx.x;
  int ti, tj, h;
  bool diag;
  if (b < 992) {
    const int q = b >> 1;
    h = b & 1;
    int bb = q;
    ti = 0;
    while (bb >= 31 - ti) { bb -= 31 - ti; ++ti; }
    tj = ti + 1 + bb;
    diag = false;
  } else {
    ti = tj = b - 992;
    h = 0;
    diag = true;
  }

  const int t = threadIdx.x;
  const int w = t >> 6;
  const int lane = t & 63;
  const int l15 = lane & 15;
  const int lg = lane >> 4;

  __shared__ __align__(16) unsigned short buf[4][2][32][64];
  __shared__ float4 relA[4][2][32], relB[4][2][32];
  __shared__ float di[4][32][3], dj[4][32][3];

  bf16x8 wf[12];
#pragma unroll
  for (int f = 0; f < 12; ++f)
    wf[f] = *(const bf16x8*)&pw[(f * 64 + lane) * 8];

  float b3v[16], c2v[16];
#pragma unroll
  for (int mt = 0; mt < 4; ++mt)
#pragma unroll
    for (int r = 0; r < 4; ++r) {
      const int d = mt * 16 + lg * 4 + r;
      b3v[mt * 4 + r] = b3p[d];
      c2v[mt * 4 + r] = c2g[d];
    }
  const float cb2q = cb2[0];  // ma carries 0.25/l
  if (lane < 32) {
    const int j = lane;
#pragma unroll
    for (int k2 = 0; k2 < 3; ++k2) { di[w][j][k2] = 0.f; dj[w][j][k2] = 0.f; }
    const uint4 z4 = make_uint4(0, 0, 0, 0);
#pragma unroll
    for (int s = 0; s < 2; ++s) {
      unsigned short* rp = &buf[w][s][j][0];
      *(uint4*)&rp[(1 ^ (j & 7)) * 8] = z4;
      *(uint4*)&rp[(2 ^ (j & 7)) * 8] = z4;
      *(uint4*)&rp[(3 ^ (j & 7)) * 8] = z4;
    }
  }

  f32x4 acc[2][4][2];

  for (int u = 0; u < 2; ++u) {
    int dgnb[2];
#pragma unroll
    for (int s = 0; s < 2; ++s) {
      const int c = u * 2 + s;
      dgnb[s] = diag ? (c * 4 + w + 1) : (h * 16 + c * 4 + w);
    }

    // ---- enc + rel + ma, both chunks ----
#pragma unroll
    for (int s = 0; s < 2; ++s) {
      const int dgn = dgnb[s];
      const int p = lane & 31;
      const int hhalf = lane >> 5;
      const int ig = ti * 32 + p;
      const int jj = (p + dgn) & 31;
      const int jg = tj * 32 + jj;
      const float rx = coors[ig * 3 + 0] - coors[jg * 3 + 0];
      const float ry = coors[ig * 3 + 1] - coors[jg * 3 + 1];
      const float rz = coors[ig * 3 + 2] - coors[jg * 3 + 2];
      const float rd = rx * rx + ry * ry + rz * rz;
      unsigned short* rp = &buf[w][s][p][0];
      if (hhalf == 0) {
        float mi = bu(ma[ig * 1024 + jg]);
        float mj = bu(ma[jg * 1024 + ig]);
        if (diag && dgn == 16 && p >= 16) { mi = 0.f; mj = 0.f; }
        relA[w][s][p] = make_float4(mi * rx, mi * ry, mi * rz, 0.f);
        relB[w][s][p] = make_float4(mj * rx, mj * ry, mj * rz, 0.f);
        *(uint2*)&rp[(0 ^ (p & 7)) * 8] =
            make_uint2(pk2(__sinf(rd), __sinf(rd * 0.5f)),
                       pk2(__sinf(rd * 0.25f), __sinf(rd * 0.125f)));
        *(unsigned*)&rp[(1 ^ (p & 7)) * 8] = pk2(rd, 1.0f);
      } else {
        *(uint2*)&rp[((0 ^ (p & 7)) * 8) + 4] =
            make_uint2(pk2(__cosf(rd), __cosf(rd * 0.5f)),
                       pk2(__cosf(rd * 0.25f), __cosf(rd * 0.125f)));
      }
    }

    // ---- GEMM1 both chunks (16 independent MFMAs) ----
#pragma unroll
    for (int s = 0; s < 2; ++s)
#pragma unroll
      for (int mt = 0; mt < 4; ++mt)
#pragma unroll
        for (int nt = 0; nt < 2; ++nt)
          acc[s][mt][nt] = (f32x4){0.f, 0.f, 0.f, 0.f};
    {
      bf16x8 bf0[2], bf1[2];
      const int j0 = l15, j1 = 16 + l15;
#pragma unroll
      for (int s = 0; s < 2; ++s) {
        bf0[s] = *(const bf16x8*)&buf[w][s][j0][(lg ^ (j0 & 7)) * 8];
        bf1[s] = *(const bf16x8*)&buf[w][s][j1][(lg ^ (j1 & 7)) * 8];
      }
#pragma unroll
      for (int mt = 0; mt < 4; ++mt)
#pragma unroll
        for (int s = 0; s < 2; ++s) {
          acc[s][mt][0] = __builtin_amdgcn_mfma_f32_16x16x32_bf16(wf[mt], bf0[s], acc[s][mt][0], 0, 0, 0);
          acc[s][mt][1] = __builtin_amdgcn_mfma_f32_16x16x32_bf16(wf[mt], bf1[s], acc[s][mt][1], 0, 0, 0);
        }
    }

    // ---- silu both chunks -> same slots ----
#pragma unroll
    for (int s = 0; s < 2; ++s)
#pragma unroll
      for (int mt = 0; mt < 4; ++mt)
#pragma unroll
        for (int nt = 0; nt < 2; ++nt) {
          const f32x4 a = acc[s][mt][nt];
          const unsigned lo = pk2(silu_f(a[0]), silu_f(a[1]));
          const unsigned hi = pk2(silu_f(a[2]), silu_f(a[3]));
          const int j = nt * 16 + l15;
          const int g = mt * 2 + (lg >> 1);
          *(uint2*)&buf[w][s][j][((g ^ (j & 7)) * 8) + (lg & 1) * 4] = make_uint2(lo, hi);
        }

    // ---- GEMM2 both chunks ----
#pragma unroll
    for (int s = 0; s < 2; ++s)
#pragma unroll
      for (int mt = 0; mt < 4; ++mt)
#pragma unroll
        for (int nt = 0; nt < 2; ++nt)
          acc[s][mt][nt] = (f32x4){b3v[mt * 4 + 0], b3v[mt * 4 + 1], b3v[mt * 4 + 2], b3v[mt * 4 + 3]};
#pragma unroll
    for (int ks = 0; ks < 2; ++ks) {
      const int gi = ks * 4 + lg;
      const int j0 = l15, j1 = 16 + l15;
      bf16x8 bf0[2], bf1[2];
#pragma unroll
      for (int s = 0; s < 2; ++s) {
        bf0[s] = *(const bf16x8*)&buf[w][s][j0][(gi ^ (j0 & 7)) * 8];
        bf1[s] = *(const bf16x8*)&buf[w][s][j1][(gi ^ (j1 & 7)) * 8];
      }
#pragma unroll
      for (int mt = 0; mt < 4; ++mt)
#pragma unroll
        for (int s = 0; s < 2; ++s) {
          acc[s][mt][0] = __builtin_amdgcn_mfma_f32_16x16x32_bf16(wf[4 + mt * 2 + ks], bf0[s], acc[s][mt][0], 0, 0, 0);
          acc[s][mt][1] = __builtin_amdgcn_mfma_f32_16x16x32_bf16(wf[4 + mt * 2 + ks], bf1[s], acc[s][mt][1], 0, 0, 0);
        }
    }

    // ---- epilogue both chunks ----
#pragma unroll
    for (int s = 0; s < 2; ++s) {
      const int dgn = dgnb[s];
#pragma unroll
      for (int nt = 0; nt < 2; ++nt) {
        float cwp = cb2q;
#pragma unroll
        for (int mt = 0; mt < 4; ++mt) {
          const f32x4 a = acc[s][mt][nt];
#pragma unroll
          for (int r = 0; r < 4; ++r) cwp += silu_f(a[r]) * c2v[mt * 4 + r];
        }
        cwp += __shfl_xor(cwp, 16);
        cwp += __shfl_xor(cwp, 32);
        if (lg == 0) {
          const int p = nt * 16 + l15;
          const int jj = (p + dgn) & 31;
          const float4 rA = relA[w][s][p];
          const float4 rB = relB[w][s][p];
          di[w][p][0] += cwp * rA.x; di[w][p][1] += cwp * rA.y; di[w][p][2] += cwp * rA.z;
          dj[w][jj][0] -= cwp * rB.x; dj[w][jj][1] -= cwp * rB.y; dj[w][jj][2] -= cwp * rB.z;
        }
      }
    }
  }

  __syncthreads();
  if (!diag) {
    if (t < 96) {
      const int p = t / 3, k = t % 3;
      const float s = di[0][p][k] + di[1][p][k] + di[2][p][k] + di[3][p][k];
      partial[(tj * 2 + h) * 3072 + (ti * 32 + p) * 3 + k] = s;
    } else if (t < 192) {
      const int u = t - 96, q2 = u / 3, k = u % 3;
      const float s = dj[0][q2][k] + dj[1][q2][k] + dj[2][q2][k] + dj[3][q2][k];
      partial[(ti * 2 + h) * 3072 + (tj * 32 + q2) * 3 + k] = s;
    }
  } else {
    if (t < 96) {
      const int p = t / 3, k = t % 3;
      const float s = di[0][p][k] + di[1][p][k] + di[2][p][k] + di[3][p][k]
                    + dj[0][p][k] + dj[1][p][k] + dj[2][p][k] + dj[3][p][k];
      partial[(ti * 2) * 3072 + (ti * 32 + p) * 3 + k] = s;
    }
  }
}

// ---------------- K_finalize: reduce 64 slabs, apply gate ----------------
__global__ __launch_bounds__(256) void k_finalize(
    const float* __restrict__ coors, const float* __restrict__ partial,
    const float* __restrict__ gate, float* __restrict__ outc) {
  const int idx = blockIdx.x * 256 + threadIdx.x;  // 0..3071 = i*3+k
  if (idx < 3072) {
    float s = 0.f;
#pragma unroll
    for (int sl = 0; sl < 64; ++sl) s += partial[sl * 3072 + idx];
    outc[idx] = coors[idx] + s * gate[idx / 3];
  }
}

extern "C" void kernel_launch(void* const* d_in, const int* in_sizes, int n_in,
                              void* d_out, int out_size, void* d_ws, size_t ws_size,
                              hipStream_t stream) {
  const float* feats = (const float*)d_in[0];
  const float* coors = (const float*)d_in[1];
  const float* qkv_w = (const float*)d_in[2];
  const float* out_w = (const float*)d_in[3];
  const float* out_b = (const float*)d_in[4];
  const float* ew1 = (const float*)d_in[5];
  const float* eb1 = (const float*)d_in[6];
  const float* ew2 = (const float*)d_in[7];
  const float* eb2 = (const float*)d_in[8];
  const float* cw1 = (const float*)d_in[9];
  const float* cb1 = (const float*)d_in[10];
  const float* cw2 = (const float*)d_in[11];
  const float* cb2 = (const float*)d_in[12];
  const float* gw1 = (const float*)d_in[13];
  const float* gb1 = (const float*)d_in[14];
  const float* gw2 = (const float*)d_in[15];
  const float* gb2 = (const float*)d_in[16];
  const float* ln1_g = (const float*)d_in[17];
  const float* ln1_b = (const float*)d_in[18];
  const float* ln2_g = (const float*)d_in[19];
  const float* ln2_b = (const float*)d_in[20];
  const float* fw1 = (const float*)d_in[21];
  const float* fb1 = (const float*)d_in[22];
  const float* fw2 = (const float*)d_in[23];
  const float* fb2 = (const float*)d_in[24];

  float* ws = (float*)d_ws;
  float* xn = ws;                                        // 65536
  float* qkv = ws + 65536;                               // 196608
  float* gate = ws + 262144;                             // 1024
  unsigned short* pw = (unsigned short*)(ws + 263168);   // 6144 ushorts = 3072 floats
  float* b3p = ws + 266240;                              // 64
  float* l_ws = ws + 266304;                             // 65536
  float* pv_ws = ws + 331840;                            // 1048576
  float* partial = ws + 1380416;                         // 196608 (64 slabs x 1024 x 3)
  unsigned short* P = (unsigned short*)(ws + 1577024);   // 4M ushorts = 2097152 floats
  unsigned short* ma = P;                                // aliases P_0 plane

  float* xout = (float*)d_out;
  float* coorout = xout + 65536;

  hipLaunchKernelGGL(k_ln1_qkv_prep, dim3(257), dim3(256), 0, stream,
                     feats, ln1_g, ln1_b, qkv_w, xn, qkv,
                     ew1, eb1, ew2, cw1, eb2, cb1, pw, b3p);
  hipLaunchKernelGGL(k_scores, dim3(16, 16), dim3(256), 0, stream, qkv, P, l_ws, pv_ws);
  hipLaunchKernelGGL(k_meanattn, dim3(16, 16), dim3(256), 0, stream, P, l_ws, ma);
  hipLaunchKernelGGL(k_ffn_gate, dim3(N), dim3(256), 0, stream, pv_ws, l_ws, xn,
                     out_w, out_b, ln2_g, ln2_b,
                     fw1, fb1, fw2, fb2, gw1, gb1, gw2, gb2, xout, gate);
  hipLaunchKernelGGL(k_pair, dim3(1024), dim3(256), 0, stream, coors, ma, pw,
                     b3p, cw2, cb2, partial);
  hipLaunchKernelGGL(k_finalize, dim3(12), dim3(256), 0, stream, coors, partial, gate, coorout);
}

// Round 15
// 104.885 us; speedup vs baseline: 1.0575x; 1.0008x over previous
//
#include <hip/hip_runtime.h>
#include <hip/hip_bf16.h>

#define N 1024
#define D 64

typedef __attribute__((ext_vector_type(8))) short bf16x8;
typedef __attribute__((ext_vector_type(4))) float f32x4;

__device__ __forceinline__ unsigned short f2b(float v) {
  unsigned u = __float_as_uint(v);
  u += 0x7fffu + ((u >> 16) & 1u);
  return (unsigned short)(u >> 16);
}
__device__ __forceinline__ unsigned short f2bc(float v) {
  union { __hip_bfloat16 h; unsigned short u; } r;
  r.h = __float2bfloat16(v);
  return r.u;
}
__device__ __forceinline__ unsigned pk2(float a, float b) {
  union { __hip_bfloat162 h; unsigned u; } r;
  r.h = __hip_bfloat162(__float2bfloat16(a), __float2bfloat16(b));
  return r.u;
}
__device__ __forceinline__ float bu(unsigned short u) {
  return __uint_as_float(((unsigned)u) << 16);
}
__device__ __forceinline__ float silu_f(float x) {
  return x * __builtin_amdgcn_rcpf(1.f + __expf(-x));
}
__device__ __forceinline__ float sigm_f(float x) {
  return __builtin_amdgcn_rcpf(1.f + __expf(-x));
}

// ---------------- K1: LN1 + QKV (4 rows/block) ----------------
__global__ __launch_bounds__(256) void k_ln1_qkv(
    const float* __restrict__ feats, const float* __restrict__ g, const float* __restrict__ b,
    const float* __restrict__ qkv_w, float* __restrict__ xn, float* __restrict__ qkv) {
  __shared__ float xs[4 * 64];
  const int t = threadIdx.x;
  const int r = t >> 6, lane = t & 63;
  const int i = blockIdx.x * 4 + r;
  float v = feats[i * D + lane];
  float s = v;
#pragma unroll
  for (int off = 32; off; off >>= 1) s += __shfl_xor(s, off);
  const float m = s * (1.0f / 64.0f);
  const float dv = v - m;
  float vs = dv * dv;
#pragma unroll
  for (int off = 32; off; off >>= 1) vs += __shfl_xor(vs, off);
  const float var = vs * (1.0f / 64.0f);
  const float xv = dv * rsqrtf(var + 1e-5f) * g[lane] + b[lane];
  xn[i * D + lane] = xv;
  xs[r * 64 + lane] = xv;
  __syncthreads();
#pragma unroll
  for (int c = 0; c < 3; ++c) {
    const int col = lane + c * 64;
    float acc = 0.f;
#pragma unroll 8
    for (int k = 0; k < D; ++k) acc += xs[r * 64 + k] * qkv_w[k * 192 + col];
    qkv[i * 192 + col] = acc;
  }
}

// ---------------- K_prep1: wc = ew2 @ cw1, 16 blocks (was 1-block, 40us latency stall) ----
__global__ __launch_bounds__(256) void k_prep1(
    const float* __restrict__ ew2, const float* __restrict__ cw1,
    float* __restrict__ wcg) {
  const int t = threadIdx.x;
  const int r = blockIdx.x * 4 + (t >> 6);
  const int c = t & 63;
  float s = 0.f;
#pragma unroll 8
  for (int k = 0; k < 64; ++k) s += ew2[r * 64 + k] * cw1[k * 64 + c];
  wcg[r * 64 + c] = s;
}

// ---------------- K_prep2: pack bf16 A-fragments + fused bias ----------------
__global__ __launch_bounds__(256) void k_prep2(
    const float* __restrict__ ew1, const float* __restrict__ eb1,
    const float* __restrict__ wcg, const float* __restrict__ eb2,
    const float* __restrict__ cw1, const float* __restrict__ cb1,
    unsigned short* __restrict__ pw, float* __restrict__ b3p) {
  const int t = threadIdx.x;
  for (int idx = t; idx < 12 * 512; idx += 256) {
    const int e = idx & 7, l = (idx >> 3) & 63, f = idx >> 9;
    const int l15 = l & 15, lg = l >> 4;
    float v;
    if (f < 4) {
      const int d = f * 16 + l15, k = lg * 8 + e;
      v = (k < 9) ? ew1[k * 64 + d] : (k == 9 ? eb1[d] : 0.f);
    } else {
      const int gq = f - 4, d = (gq >> 1) * 16 + l15, k = (gq & 1) * 32 + lg * 8 + e;
      v = wcg[k * 64 + d];
    }
    pw[idx] = f2b(v);
  }
  if (t < 64) {
    float s = cb1[t];
#pragma unroll 8
    for (int k = 0; k < 64; ++k) s += eb2[k] * cw1[k * 64 + t];
    b3p[t] = s;
  }
}

// ---------------- K_scores: MFMA QK^T -> exp -> P (bf16) + l partials + fused PV partials ----
__global__ __launch_bounds__(256) void k_scores(
    const float* __restrict__ qkv, unsigned short* __restrict__ P,
    float* __restrict__ l_ws, float* __restrict__ pv_ws) {
  const int i0 = blockIdx.x * 64, j0 = blockIdx.y * 64, jb = blockIdx.y;
  const int t = threadIdx.x;
  const int lane = t & 63, h = t >> 6;
  const int l15 = lane & 15, lg = lane >> 4;
  const int r7 = l15 & 7;

  __shared__ __align__(16) unsigned short Qs[64 * 64];
  __shared__ __align__(16) unsigned short Ks[64 * 64];
  __shared__ __align__(16) unsigned short VTs[4 * 16 * 64];
  __shared__ __align__(16) unsigned short Ps[4 * 64 * 64];

  {
    const int si = t >> 2, q4 = t & 3;
    const int g0 = ((q4 * 2) ^ (si & 7)) * 8, g1 = ((q4 * 2 + 1) ^ (si & 7)) * 8;
    {
      const float* qr = &qkv[(i0 + si) * 192 + q4 * 16];
      float4 a0 = *(const float4*)(qr + 0), a1 = *(const float4*)(qr + 4);
      float4 a2 = *(const float4*)(qr + 8), a3 = *(const float4*)(qr + 12);
      *(uint4*)&Qs[si * 64 + g0] = make_uint4(
          pk2(a0.x * 0.125f, a0.y * 0.125f), pk2(a0.z * 0.125f, a0.w * 0.125f),
          pk2(a1.x * 0.125f, a1.y * 0.125f), pk2(a1.z * 0.125f, a1.w * 0.125f));
      *(uint4*)&Qs[si * 64 + g1] = make_uint4(
          pk2(a2.x * 0.125f, a2.y * 0.125f), pk2(a2.z * 0.125f, a2.w * 0.125f),
          pk2(a3.x * 0.125f, a3.y * 0.125f), pk2(a3.z * 0.125f, a3.w * 0.125f));
    }
    {
      const float* kr = &qkv[(j0 + si) * 192 + 64 + q4 * 16];
      float4 a0 = *(const float4*)(kr + 0), a1 = *(const float4*)(kr + 4);
      float4 a2 = *(const float4*)(kr + 8), a3 = *(const float4*)(kr + 12);
      *(uint4*)&Ks[si * 64 + g0] = make_uint4(pk2(a0.x, a0.y), pk2(a0.z, a0.w),
                                              pk2(a1.x, a1.y), pk2(a1.z, a1.w));
      *(uint4*)&Ks[si * 64 + g1] = make_uint4(pk2(a2.x, a2.y), pk2(a2.z, a2.w),
                                              pk2(a3.x, a3.y), pk2(a3.z, a3.w));
    }
    {
      const float* vr = &qkv[(j0 + si) * 192 + 128 + q4 * 16];
      float4 v0 = *(const float4*)(vr + 0), v1 = *(const float4*)(vr + 4);
      float4 v2 = *(const float4*)(vr + 8), v3 = *(const float4*)(vr + 12);
      float vv[16] = {v0.x, v0.y, v0.z, v0.w, v1.x, v1.y, v1.z, v1.w,
                      v2.x, v2.y, v2.z, v2.w, v3.x, v3.y, v3.z, v3.w};
      const int sj3 = si >> 3, sj7 = si & 7;
#pragma unroll
      for (int cc = 0; cc < 16; ++cc)
        VTs[q4 * 1024 + cc * 64 + ((sj3 ^ (cc & 7)) * 8) + sj7] = f2bc(vv[cc]);
    }
  }
  __syncthreads();

  const bf16x8 z8 = {0, 0, 0, 0, 0, 0, 0, 0};
  const int gk = ((h * 2 + (lg & 1)) ^ r7) * 8;
  bf16x8 qa[4], kb[4];
#pragma unroll
  for (int it = 0; it < 4; ++it) {
    qa[it] = *(const bf16x8*)&Qs[(it * 16 + l15) * 64 + gk];
    if (lg >= 2) qa[it] = z8;
    kb[it] = *(const bf16x8*)&Ks[(it * 16 + l15) * 64 + gk];
  }
  f32x4 acc[4][4];
#pragma unroll
  for (int it = 0; it < 4; ++it)
#pragma unroll
    for (int jt = 0; jt < 4; ++jt)
      acc[it][jt] = (f32x4){0.f, 0.f, 0.f, 0.f};
#pragma unroll
  for (int it = 0; it < 4; ++it)
#pragma unroll
    for (int jt = 0; jt < 4; ++jt)
      acc[it][jt] = __builtin_amdgcn_mfma_f32_16x16x32_bf16(qa[it], kb[jt], acc[it][jt], 0, 0, 0);

  float prow[4][4];
#pragma unroll
  for (int it = 0; it < 4; ++it)
#pragma unroll
    for (int rr = 0; rr < 4; ++rr) prow[it][rr] = 0.f;
#pragma unroll
  for (int it = 0; it < 4; ++it)
#pragma unroll
    for (int jt = 0; jt < 4; ++jt)
#pragma unroll
      for (int rr = 0; rr < 4; ++rr) {
        const float p = __expf(acc[it][jt][rr]);
        prow[it][rr] += p;
        const int irow = it * 16 + lg * 4 + rr;
        const int col = jt * 16 + l15;
        Ps[h * 4096 + irow * 64 + (((col >> 3) ^ (irow & 7)) * 8) + (col & 7)] = f2bc(p);
      }
#pragma unroll
  for (int it = 0; it < 4; ++it)
#pragma unroll
    for (int rr = 0; rr < 4; ++rr) {
      float s = prow[it][rr];
      s += __shfl_xor(s, 1); s += __shfl_xor(s, 2);
      s += __shfl_xor(s, 4); s += __shfl_xor(s, 8);
      if (l15 == 0)
        l_ws[h * 16384 + jb * 1024 + i0 + it * 16 + lg * 4 + rr] = s;
    }

  f32x4 av[4];
#pragma unroll
  for (int it = 0; it < 4; ++it) av[it] = (f32x4){0.f, 0.f, 0.f, 0.f};
#pragma unroll
  for (int ks = 0; ks < 2; ++ks) {
    const int gj = ((ks * 4 + lg) ^ r7) * 8;
    bf16x8 vb = *(const bf16x8*)&VTs[h * 1024 + l15 * 64 + gj];
#pragma unroll
    for (int it = 0; it < 4; ++it) {
      bf16x8 pa = *(const bf16x8*)&Ps[h * 4096 + (it * 16 + l15) * 64 + gj];
      av[it] = __builtin_amdgcn_mfma_f32_16x16x32_bf16(pa, vb, av[it], 0, 0, 0);
    }
  }
#pragma unroll
  for (int it = 0; it < 4; ++it)
#pragma unroll
    for (int rr = 0; rr < 4; ++rr)
      pv_ws[jb * 65536 + (i0 + it * 16 + lg * 4 + rr) * 64 + h * 16 + l15] = av[it][rr];

  {
    const int ir = t & 63;
    unsigned short* pg = &P[h * 1048576 + (i0 + ir) * 1024 + j0];
#pragma unroll
    for (int gg = 0; gg < 8; ++gg)
      *(uint4*)&pg[gg * 8] = *(const uint4*)&Ps[h * 4096 + ir * 64 + ((gg ^ (ir & 7)) * 8)];
  }
}

// ---------------- K_meanattn: ma[i][j] = 0.25*sum_h P_h[i][j]/l_h[i] (bf16) ----------
__global__ __launch_bounds__(256) void k_meanattn(
    const unsigned short* P, const float* __restrict__ l_ws, unsigned short* ma) {
  const int i0 = blockIdx.x * 64, j0 = blockIdx.y * 64;
  const int t = threadIdx.x;
  __shared__ float invl[4][64];
  {
    const int h = t >> 6, r = t & 63;
    float s = 0.f;
#pragma unroll
    for (int jt = 0; jt < 16; ++jt) s += l_ws[h * 16384 + jt * 1024 + i0 + r];
    invl[h][r] = 0.25f * __builtin_amdgcn_rcpf(s);
  }
  __syncthreads();
  {
    const int r = t >> 2, cg = t & 3;
    float v[16];
#pragma unroll
    for (int k = 0; k < 16; ++k) v[k] = 0.f;
#pragma unroll
    for (int h = 0; h < 4; ++h) {
      const unsigned short* pr = &P[h * 1048576 + (i0 + r) * 1024 + j0 + cg * 16];
      uint4 a = *(const uint4*)pr;
      uint4 b2 = *(const uint4*)(pr + 8);
      const float sh = invl[h][r];
      unsigned uu[8] = {a.x, a.y, a.z, a.w, b2.x, b2.y, b2.z, b2.w};
#pragma unroll
      for (int q = 0; q < 8; ++q) {
        v[q * 2 + 0] += sh * bu((unsigned short)(uu[q] & 0xffffu));
        v[q * 2 + 1] += sh * bu((unsigned short)(uu[q] >> 16));
      }
    }
    unsigned out[8];
#pragma unroll
    for (int q = 0; q < 8; ++q) out[q] = pk2(v[2 * q], v[2 * q + 1]);
    unsigned short* mr = &ma[(i0 + r) * 1024 + j0 + cg * 16];
    *(uint4*)mr = make_uint4(out[0], out[1], out[2], out[3]);
    *(uint4*)(mr + 8) = make_uint4(out[4], out[5], out[6], out[7]);
  }
}

// ---------------- K3: msg combine + out-proj + residual + LN2 + FFN + gate ----------------
__global__ __launch_bounds__(256) void k_ffn_gate(
    const float* __restrict__ pv_ws, const float* __restrict__ l_ws,
    const float* __restrict__ xn,
    const float* __restrict__ out_w, const float* __restrict__ out_b,
    const float* __restrict__ ln2_g, const float* __restrict__ ln2_b,
    const float* __restrict__ fw1, const float* __restrict__ fb1,
    const float* __restrict__ fw2, const float* __restrict__ fb2,
    const float* __restrict__ gw1, const float* __restrict__ gb1,
    const float* __restrict__ gw2, const float* __restrict__ gb2,
    float* __restrict__ xout, float* __restrict__ gate) {
  const int i = blockIdx.x, t = threadIdx.x;
  __shared__ float msgv[64], xs[64], x1s[64], hs[256];
  if (t < 64) {
    float ls = 0.f;
#pragma unroll
    for (int jt = 0; jt < 16; ++jt) ls += l_ws[(t >> 4) * 16384 + jt * 1024 + i];
    const float invh = __builtin_amdgcn_rcpf(ls);
    float s = 0.f;
#pragma unroll
    for (int jt = 0; jt < 16; ++jt) s += pv_ws[jt * 65536 + i * 64 + t];
    msgv[t] = s * invh;
  }
  __syncthreads();
  if (t < 64) {
    float o = out_b[t];
#pragma unroll 8
    for (int k = 0; k < 64; ++k) o += msgv[k] * out_w[k * 64 + t];
    const float v = xn[i * 64 + t] + o;
    x1s[t] = v;
    float s = v;
#pragma unroll
    for (int off = 32; off; off >>= 1) s += __shfl_xor(s, off);
    const float m = s * (1.f / 64.f);
    const float dv = v - m;
    float vs = dv * dv;
#pragma unroll
    for (int off = 32; off; off >>= 1) vs += __shfl_xor(vs, off);
    xs[t] = dv * rsqrtf(vs * (1.f / 64.f) + 1e-5f) * ln2_g[t] + ln2_b[t];
  }
  __syncthreads();
  float a = fb1[t];
#pragma unroll 8
  for (int k = 0; k < 64; ++k) a += xs[k] * fw1[k * 256 + t];
  const float ge = 0.5f * a * (1.f + erff(a * 0.70710678118f));
  hs[t] = ge;
  __syncthreads();
  if (t < 64) {
    float o = fb2[t];
#pragma unroll 8
    for (int k = 0; k < 256; ++k) o += hs[k] * fw2[k * 64 + t];
    const float xo = x1s[t] + o;
    xout[i * 64 + t] = xo;
    xs[t] = xo;
  }
  __syncthreads();
  if (t < 64) {
    float a2 = gb1[t];
#pragma unroll 8
    for (int k = 0; k < 64; ++k) a2 += xs[k] * gw1[k * 64 + t];
    const float sg = a2 * sigm_f(a2);
    float pp = sg * gw2[t];
#pragma unroll
    for (int off = 32; off; off >>= 1) pp += __shfl_xor(pp, off);
    if (t == 0) gate[i] = sigm_f(pp + gb2[0]);
  }
}

// ---------------- K4: symmetric-pair MFMA, balanced 1024 blocks, 2-chunk ILP ------
__global__ __launch_bounds__(256) void k_pair(
    const float* __restrict__ coors, const unsigned short* __restrict__ ma,
    const unsigned short* __restrict__ pw,
    const float* __restrict__ b3p, const float* __restrict__ c2g,
    const float* __restrict__ cb2, float* __restrict__ partial) {
  const int b = blockIdx.x;
  int ti, tj, h;
  bool diag;
  if (b < 992) {
    const int q = b >> 1;
    h = b & 1;
    int bb = q;
    ti = 0;
    while (bb >= 31 - ti) { bb -= 31 - ti; ++ti; }
    tj = ti + 1 + bb;
    diag = false;
  } else {
    ti = tj = b - 992;
    h = 0;
    diag = true;
  }

  const int t = threadIdx.x;
  const int w = t >> 6;
  const int lane = t & 63;
  const int l15 = lane & 15;
  const int lg = lane >> 4;

  __shared__ __align__(16) unsigned short buf[4][2][32][64];
  __shared__ float4 relA[4][2][32], relB[4][2][32];
  __shared__ float di[4][32][3], dj[4][32][3];

  bf16x8 wf[12];
#pragma unroll
  for (int f = 0; f < 12; ++f)
    wf[f] = *(const bf16x8*)&pw[(f * 64 + lane) * 8];

  float b3v[16], c2v[16];
#pragma unroll
  for (int mt = 0; mt < 4; ++mt)
#pragma unroll
    for (int r = 0; r < 4; ++r) {
      const int d = mt * 16 + lg * 4 + r;
      b3v[mt * 4 + r] = b3p[d];
      c2v[mt * 4 + r] = c2g[d];
    }
  const float cb2q = cb2[0];  // ma carries 0.25/l
  if (lane < 32) {
    const int j = lane;
#pragma unroll
    for (int k2 = 0; k2 < 3; ++k2) { di[w][j][k2] = 0.f; dj[w][j][k2] = 0.f; }
    const uint4 z4 = make_uint4(0, 0, 0, 0);
#pragma unroll
    for (int s = 0; s < 2; ++s) {
      unsigned short* rp = &buf[w][s][j][0];
      *(uint4*)&rp[(1 ^ (j & 7)) * 8] = z4;
      *(uint4*)&rp[(2 ^ (j & 7)) * 8] = z4;
      *(uint4*)&rp[(3 ^ (j & 7)) * 8] = z4;
    }
  }

  f32x4 acc[2][4][2];

  for (int u = 0; u < 2; ++u) {
    int dgnb[2];
#pragma unroll
    for (int s = 0; s < 2; ++s) {
      const int c = u * 2 + s;
      dgnb[s] = diag ? (c * 4 + w + 1) : (h * 16 + c * 4 + w);
    }

    // ---- enc + rel + ma, both chunks ----
#pragma unroll
    for (int s = 0; s < 2; ++s) {
      const int dgn = dgnb[s];
      const int p = lane & 31;
      const int hhalf = lane >> 5;
      const int ig = ti * 32 + p;
      const int jj = (p + dgn) & 31;
      const int jg = tj * 32 + jj;
      const float rx = coors[ig * 3 + 0] - coors[jg * 3 + 0];
      const float ry = coors[ig * 3 + 1] - coors[jg * 3 + 1];
      const float rz = coors[ig * 3 + 2] - coors[jg * 3 + 2];
      const float rd = rx * rx + ry * ry + rz * rz;
      unsigned short* rp = &buf[w][s][p][0];
      if (hhalf == 0) {
        float mi = bu(ma[ig * 1024 + jg]);
        float mj = bu(ma[jg * 1024 + ig]);
        if (diag && dgn == 16 && p >= 16) { mi = 0.f; mj = 0.f; }
        relA[w][s][p] = make_float4(mi * rx, mi * ry, mi * rz, 0.f);
        relB[w][s][p] = make_float4(mj * rx, mj * ry, mj * rz, 0.f);
        *(uint2*)&rp[(0 ^ (p & 7)) * 8] =
            make_uint2(pk2(__sinf(rd), __sinf(rd * 0.5f)),
                       pk2(__sinf(rd * 0.25f), __sinf(rd * 0.125f)));
        *(unsigned*)&rp[(1 ^ (p & 7)) * 8] = pk2(rd, 1.0f);
      } else {
        *(uint2*)&rp[((0 ^ (p & 7)) * 8) + 4] =
            make_uint2(pk2(__cosf(rd), __cosf(rd * 0.5f)),
                       pk2(__cosf(rd * 0.25f), __cosf(rd * 0.125f)));
      }
    }

    // ---- GEMM1 both chunks (16 independent MFMAs) ----
#pragma unroll
    for (int s = 0; s < 2; ++s)
#pragma unroll
      for (int mt = 0; mt < 4; ++mt)
#pragma unroll
        for (int nt = 0; nt < 2; ++nt)
          acc[s][mt][nt] = (f32x4){0.f, 0.f, 0.f, 0.f};
    {
      bf16x8 bf0[2], bf1[2];
      const int j0 = l15, j1 = 16 + l15;
#pragma unroll
      for (int s = 0; s < 2; ++s) {
        bf0[s] = *(const bf16x8*)&buf[w][s][j0][(lg ^ (j0 & 7)) * 8];
        bf1[s] = *(const bf16x8*)&buf[w][s][j1][(lg ^ (j1 & 7)) * 8];
      }
#pragma unroll
      for (int mt = 0; mt < 4; ++mt)
#pragma unroll
        for (int s = 0; s < 2; ++s) {
          acc[s][mt][0] = __builtin_amdgcn_mfma_f32_16x16x32_bf16(wf[mt], bf0[s], acc[s][mt][0], 0, 0, 0);
          acc[s][mt][1] = __builtin_amdgcn_mfma_f32_16x16x32_bf16(wf[mt], bf1[s], acc[s][mt][1], 0, 0, 0);
        }
    }

    // ---- silu both chunks -> same slots ----
#pragma unroll
    for (int s = 0; s < 2; ++s)
#pragma unroll
      for (int mt = 0; mt < 4; ++mt)
#pragma unroll
        for (int nt = 0; nt < 2; ++nt) {
          const f32x4 a = acc[s][mt][nt];
          const unsigned lo = pk2(silu_f(a[0]), silu_f(a[1]));
          const unsigned hi = pk2(silu_f(a[2]), silu_f(a[3]));
          const int j = nt * 16 + l15;
          const int g = mt * 2 + (lg >> 1);
          *(uint2*)&buf[w][s][j][((g ^ (j & 7)) * 8) + (lg & 1) * 4] = make_uint2(lo, hi);
        }

    // ---- GEMM2 both chunks ----
#pragma unroll
    for (int s = 0; s < 2; ++s)
#pragma unroll
      for (int mt = 0; mt < 4; ++mt)
#pragma unroll
        for (int nt = 0; nt < 2; ++nt)
          acc[s][mt][nt] = (f32x4){b3v[mt * 4 + 0], b3v[mt * 4 + 1], b3v[mt * 4 + 2], b3v[mt * 4 + 3]};
#pragma unroll
    for (int ks = 0; ks < 2; ++ks) {
      const int gi = ks * 4 + lg;
      const int j0 = l15, j1 = 16 + l15;
      bf16x8 bf0[2], bf1[2];
#pragma unroll
      for (int s = 0; s < 2; ++s) {
        bf0[s] = *(const bf16x8*)&buf[w][s][j0][(gi ^ (j0 & 7)) * 8];
        bf1[s] = *(const bf16x8*)&buf[w][s][j1][(gi ^ (j1 & 7)) * 8];
      }
#pragma unroll
      for (int mt = 0; mt < 4; ++mt)
#pragma unroll
        for (int s = 0; s < 2; ++s) {
          acc[s][mt][0] = __builtin_amdgcn_mfma_f32_16x16x32_bf16(wf[4 + mt * 2 + ks], bf0[s], acc[s][mt][0], 0, 0, 0);
          acc[s][mt][1] = __builtin_amdgcn_mfma_f32_16x16x32_bf16(wf[4 + mt * 2 + ks], bf1[s], acc[s][mt][1], 0, 0, 0);
        }
    }

    // ---- epilogue both chunks ----
#pragma unroll
    for (int s = 0; s < 2; ++s) {
      const int dgn = dgnb[s];
#pragma unroll
      for (int nt = 0; nt < 2; ++nt) {
        float cwp = cb2q;
#pragma unroll
        for (int mt = 0; mt < 4; ++mt) {
          const f32x4 a = acc[s][mt][nt];
#pragma unroll
          for (int r = 0; r < 4; ++r) cwp += silu_f(a[r]) * c2v[mt * 4 + r];
        }
        cwp += __shfl_xor(cwp, 16);
        cwp += __shfl_xor(cwp, 32);
        if (lg == 0) {
          const int p = nt * 16 + l15;
          const int jj = (p + dgn) & 31;
          const float4 rA = relA[w][s][p];
          const float4 rB = relB[w][s][p];
          di[w][p][0] += cwp * rA.x; di[w][p][1] += cwp * rA.y; di[w][p][2] += cwp * rA.z;
          dj[w][jj][0] -= cwp * rB.x; dj[w][jj][1] -= cwp * rB.y; dj[w][jj][2] -= cwp * rB.z;
        }
      }
    }
  }

  __syncthreads();
  if (!diag) {
    if (t < 96) {
      const int p = t / 3, k = t % 3;
      const float s = di[0][p][k] + di[1][p][k] + di[2][p][k] + di[3][p][k];
      partial[(tj * 2 + h) * 3072 + (ti * 32 + p) * 3 + k] = s;
    } else if (t < 192) {
      const int u = t - 96, q2 = u / 3, k = u % 3;
      const float s = dj[0][q2][k] + dj[1][q2][k] + dj[2][q2][k] + dj[3][q2][k];
      partial[(ti * 2 + h) * 3072 + (tj * 32 + q2) * 3 + k] = s;
    }
  } else {
    if (t < 96) {
      const int p = t / 3, k = t % 3;
      const float s = di[0][p][k] + di[1][p][k] + di[2][p][k] + di[3][p][k]
                    + dj[0][p][k] + dj[1][p][k] + dj[2][p][k] + dj[3][p][k];
      partial[(ti * 2) * 3072 + (ti * 32 + p) * 3 + k] = s;
    }
  }
}

// ---------------- K_finalize: reduce 64 slabs, apply gate ----------------
__global__ __launch_bounds__(256) void k_finalize(
    const float* __restrict__ coors, const float* __restrict__ partial,
    const float* __restrict__ gate, float* __restrict__ outc) {
  const int idx = blockIdx.x * 256 + threadIdx.x;  // 0..3071 = i*3+k
  if (idx < 3072) {
    float s = 0.f;
#pragma unroll
    for (int sl = 0; sl < 64; ++sl) s += partial[sl * 3072 + idx];
    outc[idx] = coors[idx] + s * gate[idx / 3];
  }
}

extern "C" void kernel_launch(void* const* d_in, const int* in_sizes, int n_in,
                              void* d_out, int out_size, void* d_ws, size_t ws_size,
                              hipStream_t stream) {
  const float* feats = (const float*)d_in[0];
  const float* coors = (const float*)d_in[1];
  const float* qkv_w = (const float*)d_in[2];
  const float* out_w = (const float*)d_in[3];
  const float* out_b = (const float*)d_in[4];
  const float* ew1 = (const float*)d_in[5];
  const float* eb1 = (const float*)d_in[6];
  const float* ew2 = (const float*)d_in[7];
  const float* eb2 = (const float*)d_in[8];
  const float* cw1 = (const float*)d_in[9];
  const float* cb1 = (const float*)d_in[10];
  const float* cw2 = (const float*)d_in[11];
  const float* cb2 = (const float*)d_in[12];
  const float* gw1 = (const float*)d_in[13];
  const float* gb1 = (const float*)d_in[14];
  const float* gw2 = (const float*)d_in[15];
  const float* gb2 = (const float*)d_in[16];
  const float* ln1_g = (const float*)d_in[17];
  const float* ln1_b = (const float*)d_in[18];
  const float* ln2_g = (const float*)d_in[19];
  const float* ln2_b = (const float*)d_in[20];
  const float* fw1 = (const float*)d_in[21];
  const float* fb1 = (const float*)d_in[22];
  const float* fw2 = (const float*)d_in[23];
  const float* fb2 = (const float*)d_in[24];

  float* ws = (float*)d_ws;
  float* xn = ws;                                        // 65536
  float* qkv = ws + 65536;                               // 196608
  float* gate = ws + 262144;                             // 1024
  unsigned short* pw = (unsigned short*)(ws + 263168);   // 6144 ushorts = 3072 floats
  float* b3p = ws + 266240;                              // 64
  float* l_ws = ws + 266304;                             // 65536
  float* pv_ws = ws + 331840;                            // 1048576
  float* partial = ws + 1380416;                         // 196608 (64 slabs x 1024 x 3)
  float* wcg = ws + 1577024;                             // 4096
  unsigned short* P = (unsigned short*)(ws + 1581120);   // 4M ushorts = 2097152 floats
  unsigned short* ma = P;                                // aliases P_0 plane

  float* xout = (float*)d_out;
  float* coorout = xout + 65536;

  hipLaunchKernelGGL(k_prep1, dim3(16), dim3(256), 0, stream, ew2, cw1, wcg);
  hipLaunchKernelGGL(k_prep2, dim3(1), dim3(256), 0, stream, ew1, eb1, wcg, eb2, cw1, cb1, pw, b3p);
  hipLaunchKernelGGL(k_ln1_qkv, dim3(256), dim3(256), 0, stream, feats, ln1_g, ln1_b, qkv_w, xn, qkv);
  hipLaunchKernelGGL(k_scores, dim3(16, 16), dim3(256), 0, stream, qkv, P, l_ws, pv_ws);
  hipLaunchKernelGGL(k_meanattn, dim3(16, 16), dim3(256), 0, stream, P, l_ws, ma);
  hipLaunchKernelGGL(k_ffn_gate, dim3(N), dim3(256), 0, stream, pv_ws, l_ws, xn,
                     out_w, out_b, ln2_g, ln2_b,
                     fw1, fb1, fw2, fb2, gw1, gb1, gw2, gb2, xout, gate);
  hipLaunchKernelGGL(k_pair, dim3(1024), dim3(256), 0, stream, coors, ma, pw,
                     b3p, cw2, cb2, partial);
  hipLaunchKernelGGL(k_finalize, dim3(12), dim3(256), 0, stream, coors, partial, gate, coorout);
}

// Round 16
// 89.616 us; speedup vs baseline: 1.2376x; 1.1704x over previous
//
#include <hip/hip_runtime.h>
#include <hip/hip_bf16.h>

#define N 1024
#define D 64

typedef __attribute__((ext_vector_type(8))) short bf16x8;
typedef __attribute__((ext_vector_type(4))) float f32x4;

__device__ __forceinline__ unsigned short f2b(float v) {
  unsigned u = __float_as_uint(v);
  u += 0x7fffu + ((u >> 16) & 1u);
  return (unsigned short)(u >> 16);
}
__device__ __forceinline__ unsigned short f2bc(float v) {
  union { __hip_bfloat16 h; unsigned short u; } r;
  r.h = __float2bfloat16(v);
  return r.u;
}
__device__ __forceinline__ unsigned pk2(float a, float b) {
  union { __hip_bfloat162 h; unsigned u; } r;
  r.h = __hip_bfloat162(__float2bfloat16(a), __float2bfloat16(b));
  return r.u;
}
__device__ __forceinline__ float bu(unsigned short u) {
  return __uint_as_float(((unsigned)u) << 16);
}
__device__ __forceinline__ float silu_f(float x) {
  return x * __builtin_amdgcn_rcpf(1.f + __expf(-x));
}
__device__ __forceinline__ float sigm_f(float x) {
  return __builtin_amdgcn_rcpf(1.f + __expf(-x));
}

// ---------------- K_front: LN1+QKV (blocks 0-255) + weight prep (blocks 256-271) ------
// Prep runs CONCURRENTLY with LN/QKV; WcT elements computed as independent 64-FMA dots
// (no wc intermediate, no cross-block dependency).
__global__ __launch_bounds__(256) void k_front(
    const float* __restrict__ feats, const float* __restrict__ g, const float* __restrict__ b,
    const float* __restrict__ qkv_w, float* __restrict__ xn, float* __restrict__ qkv,
    const float* __restrict__ ew1, const float* __restrict__ eb1,
    const float* __restrict__ ew2, const float* __restrict__ cw1,
    const float* __restrict__ eb2, const float* __restrict__ cb1,
    unsigned short* __restrict__ pw, float* __restrict__ b3p) {
  const int t = threadIdx.x;
  if (blockIdx.x >= 256) {
    const int pt = (blockIdx.x - 256) * 256 + t;  // 0..4095
    // W1T part (f<4): straight copy (bias row k=9 carries eb1)
    if (pt < 2048) {
      const int f = pt >> 9, rem = pt & 511, e = rem & 7, l = (rem >> 3) & 63;
      const int l15 = l & 15, lg = l >> 4;
      const int d = f * 16 + l15, k = lg * 8 + e;
      const float v = (k < 9) ? ew1[k * 64 + d] : (k == 9 ? eb1[d] : 0.f);
      pw[pt] = f2b(v);
    }
    // WcT part (f 4..11): one 64-FMA dot per element
    {
      const int f = 4 + (pt >> 9), rem = pt & 511, e = rem & 7, l = (rem >> 3) & 63;
      const int l15 = l & 15, lg = l >> 4;
      const int gq = f - 4, d = (gq >> 1) * 16 + l15, k = (gq & 1) * 32 + lg * 8 + e;
      float s = 0.f;
#pragma unroll 8
      for (int m = 0; m < 64; ++m) s += ew2[k * 64 + m] * cw1[m * 64 + d];
      pw[f * 512 + rem] = f2b(s);
    }
    // b3p = cb1 + cw1^T eb2
    if (pt < 64) {
      float s = cb1[pt];
#pragma unroll 8
      for (int k = 0; k < 64; ++k) s += eb2[k] * cw1[k * 64 + pt];
      b3p[pt] = s;
    }
    return;
  }
  __shared__ float xs[4 * 64];
  const int r = t >> 6, lane = t & 63;
  const int i = blockIdx.x * 4 + r;
  float v = feats[i * D + lane];
  float s = v;
#pragma unroll
  for (int off = 32; off; off >>= 1) s += __shfl_xor(s, off);
  const float m = s * (1.0f / 64.0f);
  const float dv = v - m;
  float vs = dv * dv;
#pragma unroll
  for (int off = 32; off; off >>= 1) vs += __shfl_xor(vs, off);
  const float var = vs * (1.0f / 64.0f);
  const float xv = dv * rsqrtf(var + 1e-5f) * g[lane] + b[lane];
  xn[i * D + lane] = xv;
  xs[r * 64 + lane] = xv;
  __syncthreads();
#pragma unroll
  for (int c = 0; c < 3; ++c) {
    const int col = lane + c * 64;
    float acc = 0.f;
#pragma unroll 8
    for (int k = 0; k < D; ++k) acc += xs[r * 64 + k] * qkv_w[k * 192 + col];
    qkv[i * 192 + col] = acc;
  }
}

// ---------------- K_scores: MFMA QK^T -> exp -> P (bf16) + l partials + fused PV partials ----
__global__ __launch_bounds__(256) void k_scores(
    const float* __restrict__ qkv, unsigned short* __restrict__ P,
    float* __restrict__ l_ws, float* __restrict__ pv_ws) {
  const int i0 = blockIdx.x * 64, j0 = blockIdx.y * 64, jb = blockIdx.y;
  const int t = threadIdx.x;
  const int lane = t & 63, h = t >> 6;
  const int l15 = lane & 15, lg = lane >> 4;
  const int r7 = l15 & 7;

  __shared__ __align__(16) unsigned short Qs[64 * 64];
  __shared__ __align__(16) unsigned short Ks[64 * 64];
  __shared__ __align__(16) unsigned short VTs[4 * 16 * 64];
  __shared__ __align__(16) unsigned short Ps[4 * 64 * 64];

  {
    const int si = t >> 2, q4 = t & 3;
    const int g0 = ((q4 * 2) ^ (si & 7)) * 8, g1 = ((q4 * 2 + 1) ^ (si & 7)) * 8;
    {
      const float* qr = &qkv[(i0 + si) * 192 + q4 * 16];
      float4 a0 = *(const float4*)(qr + 0), a1 = *(const float4*)(qr + 4);
      float4 a2 = *(const float4*)(qr + 8), a3 = *(const float4*)(qr + 12);
      *(uint4*)&Qs[si * 64 + g0] = make_uint4(
          pk2(a0.x * 0.125f, a0.y * 0.125f), pk2(a0.z * 0.125f, a0.w * 0.125f),
          pk2(a1.x * 0.125f, a1.y * 0.125f), pk2(a1.z * 0.125f, a1.w * 0.125f));
      *(uint4*)&Qs[si * 64 + g1] = make_uint4(
          pk2(a2.x * 0.125f, a2.y * 0.125f), pk2(a2.z * 0.125f, a2.w * 0.125f),
          pk2(a3.x * 0.125f, a3.y * 0.125f), pk2(a3.z * 0.125f, a3.w * 0.125f));
    }
    {
      const float* kr = &qkv[(j0 + si) * 192 + 64 + q4 * 16];
      float4 a0 = *(const float4*)(kr + 0), a1 = *(const float4*)(kr + 4);
      float4 a2 = *(const float4*)(kr + 8), a3 = *(const float4*)(kr + 12);
      *(uint4*)&Ks[si * 64 + g0] = make_uint4(pk2(a0.x, a0.y), pk2(a0.z, a0.w),
                                              pk2(a1.x, a1.y), pk2(a1.z, a1.w));
      *(uint4*)&Ks[si * 64 + g1] = make_uint4(pk2(a2.x, a2.y), pk2(a2.z, a2.w),
                                              pk2(a3.x, a3.y), pk2(a3.z, a3.w));
    }
    {
      const float* vr = &qkv[(j0 + si) * 192 + 128 + q4 * 16];
      float4 v0 = *(const float4*)(vr + 0), v1 = *(const float4*)(vr + 4);
      float4 v2 = *(const float4*)(vr + 8), v3 = *(const float4*)(vr + 12);
      float vv[16] = {v0.x, v0.y, v0.z, v0.w, v1.x, v1.y, v1.z, v1.w,
                      v2.x, v2.y, v2.z, v2.w, v3.x, v3.y, v3.z, v3.w};
      const int sj3 = si >> 3, sj7 = si & 7;
#pragma unroll
      for (int cc = 0; cc < 16; ++cc)
        VTs[q4 * 1024 + cc * 64 + ((sj3 ^ (cc & 7)) * 8) + sj7] = f2bc(vv[cc]);
    }
  }
  __syncthreads();

  const bf16x8 z8 = {0, 0, 0, 0, 0, 0, 0, 0};
  const int gk = ((h * 2 + (lg & 1)) ^ r7) * 8;
  bf16x8 qa[4], kb[4];
#pragma unroll
  for (int it = 0; it < 4; ++it) {
    qa[it] = *(const bf16x8*)&Qs[(it * 16 + l15) * 64 + gk];
    if (lg >= 2) qa[it] = z8;
    kb[it] = *(const bf16x8*)&Ks[(it * 16 + l15) * 64 + gk];
  }
  f32x4 acc[4][4];
#pragma unroll
  for (int it = 0; it < 4; ++it)
#pragma unroll
    for (int jt = 0; jt < 4; ++jt)
      acc[it][jt] = (f32x4){0.f, 0.f, 0.f, 0.f};
#pragma unroll
  for (int it = 0; it < 4; ++it)
#pragma unroll
    for (int jt = 0; jt < 4; ++jt)
      acc[it][jt] = __builtin_amdgcn_mfma_f32_16x16x32_bf16(qa[it], kb[jt], acc[it][jt], 0, 0, 0);

  float prow[4][4];
#pragma unroll
  for (int it = 0; it < 4; ++it)
#pragma unroll
    for (int rr = 0; rr < 4; ++rr) prow[it][rr] = 0.f;
#pragma unroll
  for (int it = 0; it < 4; ++it)
#pragma unroll
    for (int jt = 0; jt < 4; ++jt)
#pragma unroll
      for (int rr = 0; rr < 4; ++rr) {
        const float p = __expf(acc[it][jt][rr]);
        prow[it][rr] += p;
        const int irow = it * 16 + lg * 4 + rr;
        const int col = jt * 16 + l15;
        Ps[h * 4096 + irow * 64 + (((col >> 3) ^ (irow & 7)) * 8) + (col & 7)] = f2bc(p);
      }
#pragma unroll
  for (int it = 0; it < 4; ++it)
#pragma unroll
    for (int rr = 0; rr < 4; ++rr) {
      float s = prow[it][rr];
      s += __shfl_xor(s, 1); s += __shfl_xor(s, 2);
      s += __shfl_xor(s, 4); s += __shfl_xor(s, 8);
      if (l15 == 0)
        l_ws[h * 16384 + jb * 1024 + i0 + it * 16 + lg * 4 + rr] = s;
    }

  f32x4 av[4];
#pragma unroll
  for (int it = 0; it < 4; ++it) av[it] = (f32x4){0.f, 0.f, 0.f, 0.f};
#pragma unroll
  for (int ks = 0; ks < 2; ++ks) {
    const int gj = ((ks * 4 + lg) ^ r7) * 8;
    bf16x8 vb = *(const bf16x8*)&VTs[h * 1024 + l15 * 64 + gj];
#pragma unroll
    for (int it = 0; it < 4; ++it) {
      bf16x8 pa = *(const bf16x8*)&Ps[h * 4096 + (it * 16 + l15) * 64 + gj];
      av[it] = __builtin_amdgcn_mfma_f32_16x16x32_bf16(pa, vb, av[it], 0, 0, 0);
    }
  }
#pragma unroll
  for (int it = 0; it < 4; ++it)
#pragma unroll
    for (int rr = 0; rr < 4; ++rr)
      pv_ws[jb * 65536 + (i0 + it * 16 + lg * 4 + rr) * 64 + h * 16 + l15] = av[it][rr];

  {
    const int ir = t & 63;
    unsigned short* pg = &P[h * 1048576 + (i0 + ir) * 1024 + j0];
#pragma unroll
    for (int gg = 0; gg < 8; ++gg)
      *(uint4*)&pg[gg * 8] = *(const uint4*)&Ps[h * 4096 + ir * 64 + ((gg ^ (ir & 7)) * 8)];
  }
}

// ---------------- K_mid: meanattn tiles (blocks 0-255) + ffn_gate rows (256-1279) ------
__global__ __launch_bounds__(256) void k_mid(
    const unsigned short* P, const float* __restrict__ l_ws, unsigned short* ma,
    const float* __restrict__ pv_ws, const float* __restrict__ xn,
    const float* __restrict__ out_w, const float* __restrict__ out_b,
    const float* __restrict__ ln2_g, const float* __restrict__ ln2_b,
    const float* __restrict__ fw1, const float* __restrict__ fb1,
    const float* __restrict__ fw2, const float* __restrict__ fb2,
    const float* __restrict__ gw1, const float* __restrict__ gb1,
    const float* __restrict__ gw2, const float* __restrict__ gb2,
    float* __restrict__ xout, float* __restrict__ gate) {
  __shared__ float smem[448];
  const int t = threadIdx.x;
  if (blockIdx.x < 256) {
    // ---- meanattn tile ----
    const int i0 = (blockIdx.x >> 4) * 64, j0 = (blockIdx.x & 15) * 64;
    float* invl = smem;  // [4][64]
    {
      const int h = t >> 6, r = t & 63;
      float s = 0.f;
#pragma unroll
      for (int jt = 0; jt < 16; ++jt) s += l_ws[h * 16384 + jt * 1024 + i0 + r];
      invl[h * 64 + r] = 0.25f * __builtin_amdgcn_rcpf(s);
    }
    __syncthreads();
    {
      const int r = t >> 2, cg = t & 3;
      float v[16];
#pragma unroll
      for (int k = 0; k < 16; ++k) v[k] = 0.f;
#pragma unroll
      for (int h = 0; h < 4; ++h) {
        const unsigned short* pr = &P[h * 1048576 + (i0 + r) * 1024 + j0 + cg * 16];
        uint4 a = *(const uint4*)pr;
        uint4 b2 = *(const uint4*)(pr + 8);
        const float sh = invl[h * 64 + r];
        unsigned uu[8] = {a.x, a.y, a.z, a.w, b2.x, b2.y, b2.z, b2.w};
#pragma unroll
        for (int q = 0; q < 8; ++q) {
          v[q * 2 + 0] += sh * bu((unsigned short)(uu[q] & 0xffffu));
          v[q * 2 + 1] += sh * bu((unsigned short)(uu[q] >> 16));
        }
      }
      unsigned out[8];
#pragma unroll
      for (int q = 0; q < 8; ++q) out[q] = pk2(v[2 * q], v[2 * q + 1]);
      unsigned short* mr = &ma[(i0 + r) * 1024 + j0 + cg * 16];
      *(uint4*)mr = make_uint4(out[0], out[1], out[2], out[3]);
      *(uint4*)(mr + 8) = make_uint4(out[4], out[5], out[6], out[7]);
    }
    return;
  }
  // ---- ffn_gate row ----
  const int i = blockIdx.x - 256;
  float* msgv = smem;          // 64
  float* xs = smem + 64;       // 64
  float* x1s = smem + 128;     // 64
  float* hs = smem + 192;      // 256
  if (t < 64) {
    float ls = 0.f;
#pragma unroll
    for (int jt = 0; jt < 16; ++jt) ls += l_ws[(t >> 4) * 16384 + jt * 1024 + i];
    const float invh = __builtin_amdgcn_rcpf(ls);
    float s = 0.f;
#pragma unroll
    for (int jt = 0; jt < 16; ++jt) s += pv_ws[jt * 65536 + i * 64 + t];
    msgv[t] = s * invh;
  }
  __syncthreads();
  if (t < 64) {
    float o = out_b[t];
#pragma unroll 8
    for (int k = 0; k < 64; ++k) o += msgv[k] * out_w[k * 64 + t];
    const float v = xn[i * 64 + t] + o;
    x1s[t] = v;
    float s = v;
#pragma unroll
    for (int off = 32; off; off >>= 1) s += __shfl_xor(s, off);
    const float m = s * (1.f / 64.f);
    const float dv = v - m;
    float vs = dv * dv;
#pragma unroll
    for (int off = 32; off; off >>= 1) vs += __shfl_xor(vs, off);
    xs[t] = dv * rsqrtf(vs * (1.f / 64.f) + 1e-5f) * ln2_g[t] + ln2_b[t];
  }
  __syncthreads();
  float a = fb1[t];
#pragma unroll 8
  for (int k = 0; k < 64; ++k) a += xs[k] * fw1[k * 256 + t];
  const float ge = 0.5f * a * (1.f + erff(a * 0.70710678118f));
  hs[t] = ge;
  __syncthreads();
  if (t < 64) {
    float o = fb2[t];
#pragma unroll 8
    for (int k = 0; k < 256; ++k) o += hs[k] * fw2[k * 64 + t];
    const float xo = x1s[t] + o;
    xout[i * 64 + t] = xo;
    xs[t] = xo;
  }
  __syncthreads();
  if (t < 64) {
    float a2 = gb1[t];
#pragma unroll 8
    for (int k = 0; k < 64; ++k) a2 += xs[k] * gw1[k * 64 + t];
    const float sg = a2 * sigm_f(a2);
    float pp = sg * gw2[t];
#pragma unroll
    for (int off = 32; off; off >>= 1) pp += __shfl_xor(pp, off);
    if (t == 0) gate[i] = sigm_f(pp + gb2[0]);
  }
}

// ---------------- K4: symmetric-pair MFMA, balanced 1024 blocks, 2-chunk ILP ------
__global__ __launch_bounds__(256) void k_pair(
    const float* __restrict__ coors, const unsigned short* __restrict__ ma,
    const unsigned short* __restrict__ pw,
    const float* __restrict__ b3p, const float* __restrict__ c2g,
    const float* __restrict__ cb2, float* __restrict__ partial) {
  const int b = blockIdx.x;
  int ti, tj, h;
  bool diag;
  if (b < 992) {
    const int q = b >> 1;
    h = b & 1;
    int bb = q;
    ti = 0;
    while (bb >= 31 - ti) { bb -= 31 - ti; ++ti; }
    tj = ti + 1 + bb;
    diag = false;
  } else {
    ti = tj = b - 992;
    h = 0;
    diag = true;
  }

  const int t = threadIdx.x;
  const int w = t >> 6;
  const int lane = t & 63;
  const int l15 = lane & 15;
  const int lg = lane >> 4;

  __shared__ __align__(16) unsigned short buf[4][2][32][64];
  __shared__ float4 relA[4][2][32], relB[4][2][32];
  __shared__ float di[4][32][3], dj[4][32][3];

  bf16x8 wf[12];
#pragma unroll
  for (int f = 0; f < 12; ++f)
    wf[f] = *(const bf16x8*)&pw[(f * 64 + lane) * 8];

  float b3v[16], c2v[16];
#pragma unroll
  for (int mt = 0; mt < 4; ++mt)
#pragma unroll
    for (int r = 0; r < 4; ++r) {
      const int d = mt * 16 + lg * 4 + r;
      b3v[mt * 4 + r] = b3p[d];
      c2v[mt * 4 + r] = c2g[d];
    }
  const float cb2q = cb2[0];  // ma carries 0.25/l
  if (lane < 32) {
    const int j = lane;
#pragma unroll
    for (int k2 = 0; k2 < 3; ++k2) { di[w][j][k2] = 0.f; dj[w][j][k2] = 0.f; }
    const uint4 z4 = make_uint4(0, 0, 0, 0);
#pragma unroll
    for (int s = 0; s < 2; ++s) {
      unsigned short* rp = &buf[w][s][j][0];
      *(uint4*)&rp[(1 ^ (j & 7)) * 8] = z4;
      *(uint4*)&rp[(2 ^ (j & 7)) * 8] = z4;
      *(uint4*)&rp[(3 ^ (j & 7)) * 8] = z4;
    }
  }

  f32x4 acc[2][4][2];

  for (int u = 0; u < 2; ++u) {
    int dgnb[2];
#pragma unroll
    for (int s = 0; s < 2; ++s) {
      const int c = u * 2 + s;
      dgnb[s] = diag ? (c * 4 + w + 1) : (h * 16 + c * 4 + w);
    }

#pragma unroll
    for (int s = 0; s < 2; ++s) {
      const int dgn = dgnb[s];
      const int p = lane & 31;
      const int hhalf = lane >> 5;
      const int ig = ti * 32 + p;
      const int jj = (p + dgn) & 31;
      const int jg = tj * 32 + jj;
      const float rx = coors[ig * 3 + 0] - coors[jg * 3 + 0];
      const float ry = coors[ig * 3 + 1] - coors[jg * 3 + 1];
      const float rz = coors[ig * 3 + 2] - coors[jg * 3 + 2];
      const float rd = rx * rx + ry * ry + rz * rz;
      unsigned short* rp = &buf[w][s][p][0];
      if (hhalf == 0) {
        float mi = bu(ma[ig * 1024 + jg]);
        float mj = bu(ma[jg * 1024 + ig]);
        if (diag && dgn == 16 && p >= 16) { mi = 0.f; mj = 0.f; }
        relA[w][s][p] = make_float4(mi * rx, mi * ry, mi * rz, 0.f);
        relB[w][s][p] = make_float4(mj * rx, mj * ry, mj * rz, 0.f);
        *(uint2*)&rp[(0 ^ (p & 7)) * 8] =
            make_uint2(pk2(__sinf(rd), __sinf(rd * 0.5f)),
                       pk2(__sinf(rd * 0.25f), __sinf(rd * 0.125f)));
        *(unsigned*)&rp[(1 ^ (p & 7)) * 8] = pk2(rd, 1.0f);
      } else {
        *(uint2*)&rp[((0 ^ (p & 7)) * 8) + 4] =
            make_uint2(pk2(__cosf(rd), __cosf(rd * 0.5f)),
                       pk2(__cosf(rd * 0.25f), __cosf(rd * 0.125f)));
      }
    }

    // ---- GEMM1 both chunks ----
#pragma unroll
    for (int s = 0; s < 2; ++s)
#pragma unroll
      for (int mt = 0; mt < 4; ++mt)
#pragma unroll
        for (int nt = 0; nt < 2; ++nt)
          acc[s][mt][nt] = (f32x4){0.f, 0.f, 0.f, 0.f};
    {
      bf16x8 bf0[2], bf1[2];
      const int j0 = l15, j1 = 16 + l15;
#pragma unroll
      for (int s = 0; s < 2; ++s) {
        bf0[s] = *(const bf16x8*)&buf[w][s][j0][(lg ^ (j0 & 7)) * 8];
        bf1[s] = *(const bf16x8*)&buf[w][s][j1][(lg ^ (j1 & 7)) * 8];
      }
#pragma unroll
      for (int mt = 0; mt < 4; ++mt)
#pragma unroll
        for (int s = 0; s < 2; ++s) {
          acc[s][mt][0] = __builtin_amdgcn_mfma_f32_16x16x32_bf16(wf[mt], bf0[s], acc[s][mt][0], 0, 0, 0);
          acc[s][mt][1] = __builtin_amdgcn_mfma_f32_16x16x32_bf16(wf[mt], bf1[s], acc[s][mt][1], 0, 0, 0);
        }
    }

    // ---- silu both chunks ----
#pragma unroll
    for (int s = 0; s < 2; ++s)
#pragma unroll
      for (int mt = 0; mt < 4; ++mt)
#pragma unroll
        for (int nt = 0; nt < 2; ++nt) {
          const f32x4 a = acc[s][mt][nt];
          const unsigned lo = pk2(silu_f(a[0]), silu_f(a[1]));
          const unsigned hi = pk2(silu_f(a[2]), silu_f(a[3]));
          const int j = nt * 16 + l15;
          const int g = mt * 2 + (lg >> 1);
          *(uint2*)&buf[w][s][j][((g ^ (j & 7)) * 8) + (lg & 1) * 4] = make_uint2(lo, hi);
        }

    // ---- GEMM2 both chunks ----
#pragma unroll
    for (int s = 0; s < 2; ++s)
#pragma unroll
      for (int mt = 0; mt < 4; ++mt)
#pragma unroll
        for (int nt = 0; nt < 2; ++nt)
          acc[s][mt][nt] = (f32x4){b3v[mt * 4 + 0], b3v[mt * 4 + 1], b3v[mt * 4 + 2], b3v[mt * 4 + 3]};
#pragma unroll
    for (int ks = 0; ks < 2; ++ks) {
      const int gi = ks * 4 + lg;
      const int j0 = l15, j1 = 16 + l15;
      bf16x8 bf0[2], bf1[2];
#pragma unroll
      for (int s = 0; s < 2; ++s) {
        bf0[s] = *(const bf16x8*)&buf[w][s][j0][(gi ^ (j0 & 7)) * 8];
        bf1[s] = *(const bf16x8*)&buf[w][s][j1][(gi ^ (j1 & 7)) * 8];
      }
#pragma unroll
      for (int mt = 0; mt < 4; ++mt)
#pragma unroll
        for (int s = 0; s < 2; ++s) {
          acc[s][mt][0] = __builtin_amdgcn_mfma_f32_16x16x32_bf16(wf[4 + mt * 2 + ks], bf0[s], acc[s][mt][0], 0, 0, 0);
          acc[s][mt][1] = __builtin_amdgcn_mfma_f32_16x16x32_bf16(wf[4 + mt * 2 + ks], bf1[s], acc[s][mt][1], 0, 0, 0);
        }
    }

    // ---- epilogue both chunks ----
#pragma unroll
    for (int s = 0; s < 2; ++s) {
      const int dgn = dgnb[s];
#pragma unroll
      for (int nt = 0; nt < 2; ++nt) {
        float cwp = cb2q;
#pragma unroll
        for (int mt = 0; mt < 4; ++mt) {
          const f32x4 a = acc[s][mt][nt];
#pragma unroll
          for (int r = 0; r < 4; ++r) cwp += silu_f(a[r]) * c2v[mt * 4 + r];
        }
        cwp += __shfl_xor(cwp, 16);
        cwp += __shfl_xor(cwp, 32);
        if (lg == 0) {
          const int p = nt * 16 + l15;
          const int jj = (p + dgn) & 31;
          const float4 rA = relA[w][s][p];
          const float4 rB = relB[w][s][p];
          di[w][p][0] += cwp * rA.x; di[w][p][1] += cwp * rA.y; di[w][p][2] += cwp * rA.z;
          dj[w][jj][0] -= cwp * rB.x; dj[w][jj][1] -= cwp * rB.y; dj[w][jj][2] -= cwp * rB.z;
        }
      }
    }
  }

  __syncthreads();
  if (!diag) {
    if (t < 96) {
      const int p = t / 3, k = t % 3;
      const float s = di[0][p][k] + di[1][p][k] + di[2][p][k] + di[3][p][k];
      partial[(tj * 2 + h) * 3072 + (ti * 32 + p) * 3 + k] = s;
    } else if (t < 192) {
      const int u = t - 96, q2 = u / 3, k = u % 3;
      const float s = dj[0][q2][k] + dj[1][q2][k] + dj[2][q2][k] + dj[3][q2][k];
      partial[(ti * 2 + h) * 3072 + (tj * 32 + q2) * 3 + k] = s;
    }
  } else {
    if (t < 96) {
      const int p = t / 3, k = t % 3;
      const float s = di[0][p][k] + di[1][p][k] + di[2][p][k] + di[3][p][k]
                    + dj[0][p][k] + dj[1][p][k] + dj[2][p][k] + dj[3][p][k];
      partial[(ti * 2) * 3072 + (ti * 32 + p) * 3 + k] = s;
    }
  }
}

// ---------------- K_finalize: reduce 64 slabs, apply gate ----------------
__global__ __launch_bounds__(256) void k_finalize(
    const float* __restrict__ coors, const float* __restrict__ partial,
    const float* __restrict__ gate, float* __restrict__ outc) {
  const int idx = blockIdx.x * 256 + threadIdx.x;
  if (idx < 3072) {
    float s = 0.f;
#pragma unroll
    for (int sl = 0; sl < 64; ++sl) s += partial[sl * 3072 + idx];
    outc[idx] = coors[idx] + s * gate[idx / 3];
  }
}

extern "C" void kernel_launch(void* const* d_in, const int* in_sizes, int n_in,
                              void* d_out, int out_size, void* d_ws, size_t ws_size,
                              hipStream_t stream) {
  const float* feats = (const float*)d_in[0];
  const float* coors = (const float*)d_in[1];
  const float* qkv_w = (const float*)d_in[2];
  const float* out_w = (const float*)d_in[3];
  const float* out_b = (const float*)d_in[4];
  const float* ew1 = (const float*)d_in[5];
  const float* eb1 = (const float*)d_in[6];
  const float* ew2 = (const float*)d_in[7];
  const float* eb2 = (const float*)d_in[8];
  const float* cw1 = (const float*)d_in[9];
  const float* cb1 = (const float*)d_in[10];
  const float* cw2 = (const float*)d_in[11];
  const float* cb2 = (const float*)d_in[12];
  const float* gw1 = (const float*)d_in[13];
  const float* gb1 = (const float*)d_in[14];
  const float* gw2 = (const float*)d_in[15];
  const float* gb2 = (const float*)d_in[16];
  const float* ln1_g = (const float*)d_in[17];
  const float* ln1_b = (const float*)d_in[18];
  const float* ln2_g = (const float*)d_in[19];
  const float* ln2_b = (const float*)d_in[20];
  const float* fw1 = (const float*)d_in[21];
  const float* fb1 = (const float*)d_in[22];
  const float* fw2 = (const float*)d_in[23];
  const float* fb2 = (const float*)d_in[24];

  float* ws = (float*)d_ws;
  float* xn = ws;                                        // 65536
  float* qkv = ws + 65536;                               // 196608
  float* gate = ws + 262144;                             // 1024
  unsigned short* pw = (unsigned short*)(ws + 263168);   // 6144 ushorts = 3072 floats
  float* b3p = ws + 266240;                              // 64
  float* l_ws = ws + 266304;                             // 65536
  float* pv_ws = ws + 331840;                            // 1048576
  float* partial = ws + 1380416;                         // 196608 (64 slabs x 1024 x 3)
  unsigned short* P = (unsigned short*)(ws + 1577024);   // 4M ushorts = 2097152 floats
  unsigned short* ma = P;                                // aliases P_0 plane

  float* xout = (float*)d_out;
  float* coorout = xout + 65536;

  hipLaunchKernelGGL(k_front, dim3(272), dim3(256), 0, stream,
                     feats, ln1_g, ln1_b, qkv_w, xn, qkv,
                     ew1, eb1, ew2, cw1, eb2, cb1, pw, b3p);
  hipLaunchKernelGGL(k_scores, dim3(16, 16), dim3(256), 0, stream, qkv, P, l_ws, pv_ws);
  hipLaunchKernelGGL(k_mid, dim3(1280), dim3(256), 0, stream, P, l_ws, ma,
                     pv_ws, xn, out_w, out_b, ln2_g, ln2_b,
                     fw1, fb1, fw2, fb2, gw1, gb1, gw2, gb2, xout, gate);
  hipLaunchKernelGGL(k_pair, dim3(1024), dim3(256), 0, stream, coors, ma, pw,
                     b3p, cw2, cb2, partial);
  hipLaunchKernelGGL(k_finalize, dim3(12), dim3(256), 0, stream, coors, partial, gate, coorout);
}